// Round 13
// baseline (107.713 us; speedup 1.0000x reference)
//
#include <hip/hip_runtime.h>
#include <hip/hip_bf16.h>

typedef unsigned short u16;
typedef unsigned int u32;
typedef __bf16 bf16x8 __attribute__((ext_vector_type(8)));
typedef float f32x4 __attribute__((ext_vector_type(4)));
typedef u16 u16x8 __attribute__((ext_vector_type(8)));
typedef u16 u16x4 __attribute__((ext_vector_type(4)));
typedef u32 u32x4 __attribute__((ext_vector_type(4)));

#define B_ 2
#define S_ 2048
#define E_ 1024
#define H_ 16
#define Dh_ 64

static __device__ __forceinline__ u16 f2bf(float f) {
  unsigned u = __builtin_bit_cast(unsigned, f);
  u += 0x7fff + ((u >> 16) & 1);   // RNE
  return (u16)(u >> 16);
}

static __device__ __forceinline__ void gload16(const u16* g, u16* l) {
  __builtin_amdgcn_global_load_lds((const __attribute__((address_space(1))) unsigned int*)g,
                                   (__attribute__((address_space(3))) unsigned int*)l,
                                   16, 0, 0);
}

// ---------------- fused fp32 -> bf16 convert: x, Wq|Wk|Wv -> wcat ----------------
__global__ void cvt_all(const float* __restrict__ x, const float* __restrict__ wq,
                        const float* __restrict__ wk, const float* __restrict__ wv,
                        u16* __restrict__ xb, u16* __restrict__ wcat) {
  const int i = blockIdx.x * 256 + threadIdx.x;     // 0..917503, exact
  const float* src; u16x8* dst;
  if (i < 524288) {
    src = x + (size_t)i * 8;            dst = (u16x8*)xb + i;
  } else {
    const int j = i - 524288;                        // 0..393215
    dst = (u16x8*)wcat + j;
    if (j < 131072)      src = wq + (size_t)j * 8;
    else if (j < 262144) src = wk + (size_t)(j - 131072) * 8;
    else                 src = wv + (size_t)(j - 262144) * 8;
  }
  float4 a = ((const float4*)src)[0], b = ((const float4*)src)[1];
  u16x8 o;
  o[0] = f2bf(a.x); o[1] = f2bf(a.y); o[2] = f2bf(a.z); o[3] = f2bf(a.w);
  o[4] = f2bf(b.x); o[5] = f2bf(b.y); o[6] = f2bf(b.z); o[7] = f2bf(b.w);
  *dst = o;
}

// ---------------- proj (f,e) fp32 -> projT (e,f) bf16 ----------------
__global__ void transpose_cvt(const float* __restrict__ in, u16* __restrict__ outT) {
  __shared__ float t[32][33];
  const int e = blockIdx.x * 32 + threadIdx.x;
  const int f = blockIdx.y * 32 + threadIdx.y;
  t[threadIdx.y][threadIdx.x] = in[f * 1024 + e];
  __syncthreads();
  const int eo = blockIdx.x * 32 + threadIdx.y;
  const int fo = blockIdx.y * 32 + threadIdx.x;
  outT[eo * 1024 + fo] = f2bf(t[threadIdx.x][threadIdx.y]);
}

// ---------------- fused QKV GEMM: 256x256 tile, 8 waves, SINGLE barrier per K-tile ----------
// Per iter: vmcnt(0) (own stage of tile kt drained) -> s_barrier (all waves' stages landed;
// all reads of the other buffer finished) -> STAGE(kt+1 -> other buf) -> compute tile kt.
// No intra-tile barriers: quadrant phases read disjoint LDS; compiler pipelines ds_reads.
__global__ __launch_bounds__(512, 2) void qkv_gemm(const u16* __restrict__ Wcat,
                                                   const u16* __restrict__ Xm,
                                                   const float* __restrict__ bq,
                                                   const float* __restrict__ bk,
                                                   const float* __restrict__ bv,
                                                   u16* __restrict__ Qb, u16* __restrict__ Kb,
                                                   u16* __restrict__ Vtb, float qs) {
  __shared__ __align__(16) u16 Alds[2][16384];   // 256 rows x 64 k
  __shared__ __align__(16) u16 Blds[2][16384];
  const int tid = threadIdx.x;                   // 0..511
  const int wv = tid >> 6, ln = tid & 63;
  const int lq = ln & 15, lg = ln >> 4;
  const int wm = wv >> 2, wn = wv & 3;           // wave grid 2(M) x 4(N)
  const int bid = blockIdx.x;
  const int xcd = bid & 7, w = bid >> 3;         // w 0..23
  const int bx = w % 12;                         // 0..11 (M tiles; region = bx>>2)
  const int by = xcd * 2 + w / 12;               // 0..15 (N tiles)
  const int ra0 = bx * 256, rb0 = by * 256;

  // staging: thread t stages LDS chunk q*512+t of each quarter q; source col pre-swizzled
  const int r_t = tid >> 3, c_t = tid & 7;       // row-in-quarter 0..63, chunk 0..7
  const int gcol = (c_t ^ (r_t & 7)) * 8;        // swizzled source k-offset (u16)
  const u16* Asrc = Wcat + (ra0 + r_t) * 1024 + gcol;
  const u16* Bsrc = Xm   + (rb0 + r_t) * 1024 + gcol;

  // fragment read offsets (swizzled): chunk pos = (kh*4+lg) ^ (lq&7), u16 off = pos*8
  const int sc0 = (lg ^ (lq & 7)) * 8;
  const int sc1 = ((4 + lg) ^ (lq & 7)) * 8;
  const int baseA = (wm * 128 + lq) * 64;        // + mh*4096 + ii*1024 + sc
  const int baseB = (wn * 64 + lq) * 64;         // + j*1024 + sc

  f32x4 acc[8][4];
  const f32x4 z4 = {0.f, 0.f, 0.f, 0.f};
#pragma unroll
  for (int i = 0; i < 8; ++i)
#pragma unroll
    for (int j = 0; j < 4; ++j) acc[i][j] = z4;

#define SA(Q, KT, BUF) gload16(Asrc + (Q) * 65536 + (KT) * 64, &Alds[BUF][((Q) * 512 + tid) * 8])
#define SB(Q, KT, BUF) gload16(Bsrc + (Q) * 65536 + (KT) * 64, &Blds[BUF][((Q) * 512 + tid) * 8])
#define LOADA(MH, SC) do {                                                         \
    _Pragma("unroll") for (int ii = 0; ii < 4; ++ii)                               \
      af[ii] = *(const bf16x8*)&Alds[cb][baseA + (MH) * 4096 + ii * 1024 + (SC)];  \
  } while (0)
#define LOADB(DST, SC) do {                                                        \
    _Pragma("unroll") for (int j = 0; j < 4; ++j)                                  \
      DST[j] = *(const bf16x8*)&Blds[cb][baseB + j * 1024 + (SC)];                 \
  } while (0)
#define MF(MH, BQ) do {                                                            \
    _Pragma("unroll") for (int ii = 0; ii < 4; ++ii)                               \
      _Pragma("unroll") for (int j = 0; j < 4; ++j)                                \
        acc[(MH) * 4 + ii][j] =                                                    \
            __builtin_amdgcn_mfma_f32_16x16x32_bf16(af[ii], BQ[j],                 \
                                                    acc[(MH) * 4 + ii][j], 0, 0, 0); \
  } while (0)

  // prologue: stage tile 0
  SB(0, 0, 0); SB(1, 0, 0); SB(2, 0, 0); SB(3, 0, 0);
  SA(0, 0, 0); SA(1, 0, 0); SA(2, 0, 0); SA(3, 0, 0);

  for (int kt = 0; kt < 16; ++kt) {
    const int cb = kt & 1, nb = cb ^ 1;
    asm volatile("s_waitcnt vmcnt(0)" ::: "memory");   // own stage of tile kt drained
    __builtin_amdgcn_s_barrier();                      // all stages landed; old reads done
    __builtin_amdgcn_sched_barrier(0);
    if (kt < 15) {
      SB(0, kt + 1, nb); SB(1, kt + 1, nb); SB(2, kt + 1, nb); SB(3, kt + 1, nb);
      SA(0, kt + 1, nb); SA(1, kt + 1, nb); SA(2, kt + 1, nb); SA(3, kt + 1, nb);
    }
    bf16x8 af[4], bq0[4], bq1[4];
    LOADB(bq0, sc0);
    LOADB(bq1, sc1);
    LOADA(0, sc0);
    __builtin_amdgcn_s_setprio(1);
    MF(0, bq0);
    __builtin_amdgcn_s_setprio(0);
    LOADA(0, sc1);
    __builtin_amdgcn_s_setprio(1);
    MF(0, bq1);
    __builtin_amdgcn_s_setprio(0);
    LOADA(1, sc0);
    __builtin_amdgcn_s_setprio(1);
    MF(1, bq0);
    __builtin_amdgcn_s_setprio(0);
    LOADA(1, sc1);
    __builtin_amdgcn_s_setprio(1);
    MF(1, bq1);
    __builtin_amdgcn_s_setprio(0);
  }
#undef SA
#undef SB
#undef LOADA
#undef LOADB
#undef MF

  const int region = bx >> 2;  // 0=Q 1=K 2=V, block-uniform
  const float* bias = (region == 0) ? bq : (region == 1) ? bk : bv;
  const float osc = (region == 0) ? qs : 1.0f;
#pragma unroll
  for (int i = 0; i < 8; ++i) {
#pragma unroll
    for (int j = 0; j < 4; ++j) {
      const int n0 = ra0 + wm * 128 + (i >> 2) * 64 + (i & 3) * 16 + lg * 4;
      const int nl = n0 & 1023;
      const int h = nl >> 6, d = nl & 63;
      const int m = rb0 + wn * 64 + j * 16 + lq;
      const int bb = m >> 11, s = m & 2047;
      const float4 b4 = *(const float4*)&bias[nl];
      if (region < 2) {
        u16* out = (region == 0) ? Qb : Kb;
        u16x4 pk;
        pk[0] = f2bf((acc[i][j][0] + b4.x) * osc);
        pk[1] = f2bf((acc[i][j][1] + b4.y) * osc);
        pk[2] = f2bf((acc[i][j][2] + b4.z) * osc);
        pk[3] = f2bf((acc[i][j][3] + b4.w) * osc);
        *(u16x4*)&out[((bb * H_ + h) * S_ + s) * Dh_ + d] = pk;
      } else {
        const float bvv[4] = {b4.x, b4.y, b4.z, b4.w};
#pragma unroll
        for (int r = 0; r < 4; ++r)
          Vtb[((bb * H_ + h) * Dh_ + d + r) * S_ + s] = f2bf(acc[i][j][r] + bvv[r]);
      }
    }
  }
}

// ---------------- proj GEMM, 2-phase dbuf, SINGLE barrier per K-step ----------------
__global__ __launch_bounds__(256) void proj_gemm(const u16* __restrict__ Am,
                                                 const u16* __restrict__ Bm,
                                                 float* __restrict__ out) {
  __shared__ __align__(16) u16 As[2][4096];
  __shared__ __align__(16) u16 Bs[2][2048];
  const int tid = threadIdx.x;
  const int wv = tid >> 6, ln = tid & 63;
  const int lq = ln & 15, lg = ln >> 4;
  const int bid = blockIdx.x;
  const int xcd = bid & 7, within = bid >> 3;       // 0..63
  const int bx = within & 7;
  const int by = xcd * 8 + (within >> 3);           // 0..63
  const int ra0 = bx * 128, rb0 = by * 64;
  const int wra = wv >> 1, wrb = wv & 1;

  f32x4 acc[4][2];
  const f32x4 z4 = {0.f, 0.f, 0.f, 0.f};
#pragma unroll
  for (int i = 0; i < 4; ++i)
#pragma unroll
    for (int j = 0; j < 2; ++j) acc[i][j] = z4;

  const int arow = tid >> 2;
  const int acol = (tid & 3) * 8;
  const int brow = wv * 16 + (ln >> 2);
  const int bcol = (ln & 3) * 8;
  const u16* Ags = Am + (ra0 + arow) * 1024 + acol;
  const u16* Bgs = Bm + (rb0 + brow) * 1024 + bcol;

#define PSTAGE(KT, BUF) do { const int k0_ = (KT) * 32;              \
    gload16(Ags + k0_,         &As[BUF][wv * 512]);                  \
    gload16(Ags + 65536 + k0_, &As[BUF][wv * 512 + 2048]);           \
    gload16(Bgs + k0_,         &Bs[BUF][wv * 512]); } while (0)

  PSTAGE(0, 0);
  for (int kt = 0; kt < 32; ++kt) {
    const int cb = kt & 1;
    asm volatile("s_waitcnt vmcnt(0)" ::: "memory");
    __builtin_amdgcn_s_barrier();
    __builtin_amdgcn_sched_barrier(0);
    if (kt < 31) PSTAGE(kt + 1, cb ^ 1);
    bf16x8 af[4], bfr[2];
#pragma unroll
    for (int i = 0; i < 4; ++i)
      af[i] = *(const bf16x8*)&As[cb][(wra * 64 + i * 16 + lq) * 32 + lg * 8];
#pragma unroll
    for (int j = 0; j < 2; ++j)
      bfr[j] = *(const bf16x8*)&Bs[cb][(wrb * 32 + j * 16 + lq) * 32 + lg * 8];
    __builtin_amdgcn_s_setprio(1);
#pragma unroll
    for (int i = 0; i < 4; ++i)
#pragma unroll
      for (int j = 0; j < 2; ++j)
        acc[i][j] = __builtin_amdgcn_mfma_f32_16x16x32_bf16(af[i], bfr[j], acc[i][j], 0, 0, 0);
    __builtin_amdgcn_s_setprio(0);
  }
#undef PSTAGE

  const int Ar = ra0 + wra * 64, Br = rb0 + wrb * 32;
#pragma unroll
  for (int i = 0; i < 4; ++i)
#pragma unroll
    for (int j = 0; j < 2; ++j) {
      const int e0 = Ar + i * 16 + lg * 4;
      const int m = Br + j * 16 + lq;
      *(f32x4*)&out[m * 1024 + e0] = acc[i][j];
    }
}

// ---------------- flash attention: 8 waves x 16 q-rows, KVBLK=128, SINGLE barrier/tile ---------
// Per iter: vmcnt(0) -> s_barrier -> STAGE(kt+1 -> other buf) -> compute tile kt.
__global__ __launch_bounds__(512, 4) void attn_kernel(const u16* __restrict__ Q,
                                                      const u16* __restrict__ K,
                                                      const u16* __restrict__ Vt,
                                                      u16* __restrict__ Z) {
  __shared__ __align__(16) u16 Ktile[2][8192];   // 128 keys x 64 d, chunk-swizzled (mod-8)
  __shared__ __align__(16) u16 Vtile[2][8192];   // 64 d x 128 keys, chunk-swizzled (mod-16)
  const int tid = threadIdx.x;
  const int wv = tid >> 6, ln = tid & 63;
  const int lq = ln & 15, lg = ln >> 4;
  const bool lgodd = (lg & 1) != 0;
  const int id = blockIdx.x;
  const int within = id >> 3;                      // 0..63
  const int xg = id & 7;                           // XCD group (L2 locality)
  int bh, qt;
  if (within < 32) { bh = xg * 4 + (within >> 4);     qt = 15 - (within & 15); }
  else { const int w = within - 32; bh = xg * 4 + 2 + (w >> 4); qt = w & 15; }
  const int qrow = (qt << 7) + wv * 16 + lq;       // this thread's q row
  const u16* Qp = Q + (size_t)bh * S_ * Dh_;
  const u16* Kp = K + (size_t)bh * S_ * Dh_;
  const u16* Vp = Vt + (size_t)bh * Dh_ * S_;

  // staging: 1024 16B-chunks per tile kind; 512 threads x 2 chunks each
  int kgofs[2], vgrow[2], vgcol[2];
#pragma unroll
  for (int j = 0; j < 2; ++j) {
    const int p = j * 512 + tid;                   // 0..1023 chunk id
    const int gk = p ^ ((p >> 3) & 7);             // K: row=p>>3 (0..127), col swizzled mod 8
    kgofs[j] = (gk >> 3) * 64 + (gk & 7) * 8;
    vgrow[j] = p >> 4;                             // V: row=d (0..63), col swizzled mod 16
    vgcol[j] = ((p & 15) ^ ((p >> 4) & 15)) * 8;
  }
  const int sc0 = (lg ^ (lq & 7)) * 8;             // K read cols (d-half 0)
  const int sc1 = ((4 + lg) ^ (lq & 7)) * 8;       // K read cols (d-half 1)

  bf16x8 qf0 = *(const bf16x8*)&Qp[qrow * Dh_ + lg * 8];
  bf16x8 qf1 = *(const bf16x8*)&Qp[qrow * Dh_ + 32 + lg * 8];

  f32x4 o[4];
  const f32x4 z4 = {0.f, 0.f, 0.f, 0.f};
#pragma unroll
  for (int dt = 0; dt < 4; ++dt) o[dt] = z4;
  float l_lane = 0.f;

#define STAGE(KT, BUF) do { const int kb_ = (KT) * 128;                              \
    gload16(Kp + (size_t)kb_ * 64 + kgofs[0], &Ktile[BUF][wv * 512]);                \
    gload16(Kp + (size_t)kb_ * 64 + kgofs[1], &Ktile[BUF][4096 + wv * 512]);         \
    gload16(Vp + (size_t)vgrow[0] * 2048 + kb_ + vgcol[0], &Vtile[BUF][wv * 512]);   \
    gload16(Vp + (size_t)vgrow[1] * 2048 + kb_ + vgcol[1], &Vtile[BUF][4096 + wv * 512]); \
  } while (0)

  STAGE(0, 0);

  int cur = 0;
  for (int kt = 0; kt <= qt; ++kt) {
    asm volatile("s_waitcnt vmcnt(0)" ::: "memory");   // own stage of tile kt drained
    __builtin_amdgcn_s_barrier();                      // all stages landed; old reads done
    __builtin_amdgcn_sched_barrier(0);
    if (kt < qt) STAGE(kt + 1, cur ^ 1);
    const int k0 = kt * 128;
    const bool diag = (kt == qt);
    const int nkk = diag ? ((wv >> 1) + 1) : 4;    // diag: skip fully-masked 32-key slices
#pragma unroll
    for (int kk = 0; kk < 4; ++kk) {
      if (kk < nkk) {
        const int rA = (kk * 32 + lq) * 64;        // keys kk*32 + 0..15
        const int rB = rA + 1024;                  // +16 keys
        bf16x8 kA0 = *(const bf16x8*)&Ktile[cur][rA + sc0];
        bf16x8 kA1 = *(const bf16x8*)&Ktile[cur][rA + sc1];
        bf16x8 kB0 = *(const bf16x8*)&Ktile[cur][rB + sc0];
        bf16x8 kB1 = *(const bf16x8*)&Ktile[cur][rB + sc1];
        f32x4 sa = z4, sb = z4;
        __builtin_amdgcn_s_setprio(1);
        sa = __builtin_amdgcn_mfma_f32_16x16x32_bf16(kA0, qf0, sa, 0, 0, 0);
        sa = __builtin_amdgcn_mfma_f32_16x16x32_bf16(kA1, qf1, sa, 0, 0, 0);
        sb = __builtin_amdgcn_mfma_f32_16x16x32_bf16(kB0, qf0, sb, 0, 0, 0);
        sb = __builtin_amdgcn_mfma_f32_16x16x32_bf16(kB1, qf1, sb, 0, 0, 0);
        __builtin_amdgcn_s_setprio(0);
        if (diag) {
          const int keyA = k0 + kk * 32 + lg * 4;
          const int keyB = keyA + 16;
#pragma unroll
          for (int r = 0; r < 4; ++r) {
            if (keyA + r > qrow) sa[r] = -3.0e38f;
            if (keyB + r > qrow) sb[r] = -3.0e38f;
          }
        }
        // fixed-max softmax (log2 domain; scores bounded, exp2 can't overflow)
        float e0 = __builtin_amdgcn_exp2f(sa[0]);
        float e1 = __builtin_amdgcn_exp2f(sa[1]);
        float e2 = __builtin_amdgcn_exp2f(sa[2]);
        float e3 = __builtin_amdgcn_exp2f(sa[3]);
        float f0 = __builtin_amdgcn_exp2f(sb[0]);
        float f1 = __builtin_amdgcn_exp2f(sb[1]);
        float f2 = __builtin_amdgcn_exp2f(sb[2]);
        float f3 = __builtin_amdgcn_exp2f(sb[3]);
        l_lane += ((e0 + e1) + (e2 + e3)) + ((f0 + f1) + (f2 + f3));
        u32 A0, A1, B0, B1;
        asm("v_cvt_pk_bf16_f32 %0, %1, %2" : "=v"(A0) : "v"(e0), "v"(e1));
        asm("v_cvt_pk_bf16_f32 %0, %1, %2" : "=v"(A1) : "v"(e2), "v"(e3));
        asm("v_cvt_pk_bf16_f32 %0, %1, %2" : "=v"(B0) : "v"(f0), "v"(f1));
        asm("v_cvt_pk_bf16_f32 %0, %1, %2" : "=v"(B1) : "v"(f2), "v"(f3));
        // in-register P^T routing (verified R6-R12)
        asm("v_permlane32_swap_b32 %0, %1" : "+v"(A0), "+v"(B0));
        asm("v_permlane32_swap_b32 %0, %1" : "+v"(A1), "+v"(B1));
        const u32 A0x = __shfl_xor((int)A0, 16), B0x = __shfl_xor((int)B0, 16);
        const u32 A1x = __shfl_xor((int)A1, 16), B1x = __shfl_xor((int)B1, 16);
        u32x4 w;
        w[0] = lgodd ? B0x : A0;
        w[1] = lgodd ? B1x : A1;
        w[2] = lgodd ? B0 : A0x;
        w[3] = lgodd ? B1 : A1x;
        const bf16x8 pf = __builtin_bit_cast(bf16x8, w);
        const int scvk = ((kk * 4 + lg) ^ lq) * 8;
        __builtin_amdgcn_s_setprio(1);
#pragma unroll
        for (int dt = 0; dt < 4; ++dt) {
          bf16x8 vf = *(const bf16x8*)&Vtile[cur][(dt * 16 + lq) * 128 + scvk];
          o[dt] = __builtin_amdgcn_mfma_f32_16x16x32_bf16(vf, pf, o[dt], 0, 0, 0);
        }
        __builtin_amdgcn_s_setprio(0);
      }
    }
    cur ^= 1;
  }
#undef STAGE

  // epilogue: reduce row-sum across lg groups, apply 1/l and the quirk's extra /8
  float l = l_lane;
  l += __shfl_xor(l, 16);
  l += __shfl_xor(l, 32);
  const float inv = 0.125f / l;
#pragma unroll
  for (int dt = 0; dt < 4; ++dt) {
    u16x4 pko;
#pragma unroll
    for (int r = 0; r < 4; ++r) pko[r] = f2bf(o[dt][r] * inv);
    *(u16x4*)&Z[((size_t)bh * S_ + qrow) * Dh_ + dt * 16 + lg * 4] = pko;
  }
}

extern "C" void kernel_launch(void* const* d_in, const int* in_sizes, int n_in,
                              void* d_out, int out_size, void* d_ws, size_t ws_size,
                              hipStream_t stream) {
  const float* x    = (const float*)d_in[0];
  const float* Wq   = (const float*)d_in[1];
  const float* bq   = (const float*)d_in[2];
  const float* Wk   = (const float*)d_in[3];
  const float* bk   = (const float*)d_in[4];
  const float* Wv   = (const float*)d_in[5];
  const float* bv   = (const float*)d_in[6];
  const float* proj = (const float*)d_in[7];
  float* out = (float*)d_out;

  char* p = (char*)d_ws;
  u16* xb   = (u16*)p; p += (size_t)4096 * 1024 * 2;
  u16* wcat = (u16*)p; p += (size_t)3072 * 1024 * 2;
  u16* pjt  = (u16*)p; p += (size_t)1024 * 1024 * 2;
  u16* Qb   = (u16*)p; p += (size_t)4096 * 1024 * 2;
  u16* Kb   = (u16*)p; p += (size_t)4096 * 1024 * 2;
  u16* Vtb  = (u16*)p; p += (size_t)4096 * 1024 * 2;
  u16* Zb   = (u16*)p; p += (size_t)4096 * 1024 * 2;

  cvt_all<<<dim3(3584), dim3(256), 0, stream>>>(x, Wq, Wk, Wv, xb, wcat);
  transpose_cvt<<<dim3(32, 32), dim3(32, 32), 0, stream>>>(proj, pjt);

  const float qs = 0.125f * 1.44269504f;  // fold score-scale + log2e into Q
  qkv_gemm<<<dim3(192), dim3(512), 0, stream>>>(wcat, xb, bq, bk, bv, Qb, Kb, Vtb, qs);

  attn_kernel<<<dim3(512), dim3(512), 0, stream>>>(Qb, Kb, Vtb, Zb);

  proj_gemm<<<dim3(512), dim3(256), 0, stream>>>(pjt, Zb, out);
}

// Round 14
// 101.233 us; speedup vs baseline: 1.0640x; 1.0640x over previous
//
#include <hip/hip_runtime.h>
#include <hip/hip_bf16.h>

typedef unsigned short u16;
typedef unsigned int u32;
typedef __bf16 bf16x8 __attribute__((ext_vector_type(8)));
typedef float f32x4 __attribute__((ext_vector_type(4)));
typedef u16 u16x8 __attribute__((ext_vector_type(8)));
typedef u16 u16x4 __attribute__((ext_vector_type(4)));
typedef u32 u32x4 __attribute__((ext_vector_type(4)));

#define B_ 2
#define S_ 2048
#define E_ 1024
#define H_ 16
#define Dh_ 64

static __device__ __forceinline__ u16 f2bf(float f) {
  unsigned u = __builtin_bit_cast(unsigned, f);
  u += 0x7fff + ((u >> 16) & 1);   // RNE
  return (u16)(u >> 16);
}

static __device__ __forceinline__ void gload16(const u16* g, u16* l) {
  __builtin_amdgcn_global_load_lds((const __attribute__((address_space(1))) unsigned int*)g,
                                   (__attribute__((address_space(3))) unsigned int*)l,
                                   16, 0, 0);
}

// ---------------- fused fp32 -> bf16 convert: x, Wq|Wk|Wv -> wcat; proj -> projT ----------------
// blocks 0..3583: elementwise x/weights convert. blocks 3584..4607: proj transpose tiles.
__global__ void cvt_all(const float* __restrict__ x, const float* __restrict__ wq,
                        const float* __restrict__ wk, const float* __restrict__ wv,
                        const float* __restrict__ proj,
                        u16* __restrict__ xb, u16* __restrict__ wcat, u16* __restrict__ pjt) {
  __shared__ float tt[32][33];
  const int bid = blockIdx.x;
  const int tid = threadIdx.x;
  if (bid < 3584) {
    const int i = bid * 256 + tid;                   // 0..917503, exact
    const float* src; u16x8* dst;
    if (i < 524288) {
      src = x + (size_t)i * 8;            dst = (u16x8*)xb + i;
    } else {
      const int j = i - 524288;                      // 0..393215
      dst = (u16x8*)wcat + j;
      if (j < 131072)      src = wq + (size_t)j * 8;
      else if (j < 262144) src = wk + (size_t)(j - 131072) * 8;
      else                 src = wv + (size_t)(j - 262144) * 8;
    }
    float4 a = ((const float4*)src)[0], b = ((const float4*)src)[1];
    u16x8 o;
    o[0] = f2bf(a.x); o[1] = f2bf(a.y); o[2] = f2bf(a.z); o[3] = f2bf(a.w);
    o[4] = f2bf(b.x); o[5] = f2bf(b.y); o[6] = f2bf(b.z); o[7] = f2bf(b.w);
    *dst = o;
  } else {
    const int tb = bid - 3584;                       // 0..1023
    const int e0 = (tb & 31) * 32, f0 = (tb >> 5) * 32;
    const int tx = tid & 31, ty = tid >> 5;          // 32 x 8
#pragma unroll
    for (int r = 0; r < 4; ++r) {
      const int row = ty + r * 8;
      tt[row][tx] = proj[(f0 + row) * 1024 + e0 + tx];
    }
    __syncthreads();
#pragma unroll
    for (int r = 0; r < 4; ++r) {
      const int row = ty + r * 8;
      pjt[(e0 + row) * 1024 + f0 + tx] = f2bf(tt[tx][row]);
    }
  }
}

// ---------------- fused QKV GEMM: 256x256 tile, 8 waves, 4-phase/K-tile (R12-proven) ----------
__global__ __launch_bounds__(512, 2) void qkv_gemm(const u16* __restrict__ Wcat,
                                                   const u16* __restrict__ Xm,
                                                   const float* __restrict__ bq,
                                                   const float* __restrict__ bk,
                                                   const float* __restrict__ bv,
                                                   u16* __restrict__ Qb, u16* __restrict__ Kb,
                                                   u16* __restrict__ Vtb, float qs) {
  __shared__ __align__(16) u16 Alds[2][16384];   // 256 rows x 64 k
  __shared__ __align__(16) u16 Blds[2][16384];
  const int tid = threadIdx.x;                   // 0..511
  const int wv = tid >> 6, ln = tid & 63;
  const int lq = ln & 15, lg = ln >> 4;
  const int wm = wv >> 2, wn = wv & 3;           // wave grid 2(M) x 4(N)
  const int bid = blockIdx.x;
  const int xcd = bid & 7, w = bid >> 3;         // w 0..23
  const int bx = w % 12;                         // 0..11 (M tiles; region = bx>>2)
  const int by = xcd * 2 + w / 12;               // 0..15 (N tiles)
  const int ra0 = bx * 256, rb0 = by * 256;

  // staging: thread t stages LDS chunk q*512+t of each quarter q; source col pre-swizzled
  const int r_t = tid >> 3, c_t = tid & 7;       // row-in-quarter 0..63, chunk 0..7
  const int gcol = (c_t ^ (r_t & 7)) * 8;        // swizzled source k-offset (u16)
  const u16* Asrc = Wcat + (ra0 + r_t) * 1024 + gcol;
  const u16* Bsrc = Xm   + (rb0 + r_t) * 1024 + gcol;

  // fragment read offsets (swizzled): chunk pos = (kh*4+lg) ^ (lq&7), u16 off = pos*8
  const int sc0 = (lg ^ (lq & 7)) * 8;
  const int sc1 = ((4 + lg) ^ (lq & 7)) * 8;
  const int baseA = (wm * 128 + lq) * 64;        // + mh*4096 + ii*1024 + sc
  const int baseB = (wn * 64 + lq) * 64;         // + j*1024 + sc

  f32x4 acc[8][4];
  const f32x4 z4 = {0.f, 0.f, 0.f, 0.f};
#pragma unroll
  for (int i = 0; i < 8; ++i)
#pragma unroll
    for (int j = 0; j < 4; ++j) acc[i][j] = z4;

#define SA(Q, KT, BUF) gload16(Asrc + (Q) * 65536 + (KT) * 64, &Alds[BUF][((Q) * 512 + tid) * 8])
#define SB(Q, KT, BUF) gload16(Bsrc + (Q) * 65536 + (KT) * 64, &Blds[BUF][((Q) * 512 + tid) * 8])
#define LOADA(MH, SC) do {                                                         \
    _Pragma("unroll") for (int ii = 0; ii < 4; ++ii)                               \
      af[ii] = *(const bf16x8*)&Alds[cb][baseA + (MH) * 4096 + ii * 1024 + (SC)];  \
  } while (0)
#define LOADB(DST, SC) do {                                                        \
    _Pragma("unroll") for (int j = 0; j < 4; ++j)                                  \
      DST[j] = *(const bf16x8*)&Blds[cb][baseB + j * 1024 + (SC)];                 \
  } while (0)
#define MF(MH, BQ) do {                                                            \
    _Pragma("unroll") for (int ii = 0; ii < 4; ++ii)                               \
      _Pragma("unroll") for (int j = 0; j < 4; ++j)                                \
        acc[(MH) * 4 + ii][j] =                                                    \
            __builtin_amdgcn_mfma_f32_16x16x32_bf16(af[ii], BQ[j],                 \
                                                    acc[(MH) * 4 + ii][j], 0, 0, 0); \
  } while (0)

  // prologue: stage tile 0; order matters: last two issued = A-q1, A-q3
  SB(0, 0, 0); SB(1, 0, 0); SB(2, 0, 0); SB(3, 0, 0);
  SA(0, 0, 0); SA(2, 0, 0); SA(1, 0, 0); SA(3, 0, 0);

  for (int kt = 0; kt < 16; ++kt) {
    const int cb = kt & 1, nb = cb ^ 1;
    const bool st = (kt < 15);
    // tile boundary: all B + A-q0,q2 of tile kt landed; A-q1,q3 may fly
    asm volatile("s_waitcnt vmcnt(2)" ::: "memory");
    __builtin_amdgcn_s_barrier();
    __builtin_amdgcn_sched_barrier(0);
    bf16x8 af[4], bq0[4], bq1[4];
    // phase 0: (mh0, kh0)
    LOADA(0, sc0);
    LOADB(bq0, sc0);
    if (st) { SB(0, kt + 1, nb); SB(1, kt + 1, nb); }
    __builtin_amdgcn_s_barrier();
    asm volatile("s_waitcnt lgkmcnt(0)" ::: "memory");
    __builtin_amdgcn_sched_barrier(0);
    __builtin_amdgcn_s_setprio(1);
    MF(0, bq0);
    __builtin_amdgcn_s_setprio(0);
    __builtin_amdgcn_s_barrier();
    // phase 1: (mh0, kh1)
    LOADA(0, sc1);
    LOADB(bq1, sc1);
    if (st) { SB(2, kt + 1, nb); SB(3, kt + 1, nb); }
    __builtin_amdgcn_s_barrier();
    asm volatile("s_waitcnt lgkmcnt(0)" ::: "memory");
    __builtin_amdgcn_sched_barrier(0);
    __builtin_amdgcn_s_setprio(1);
    MF(0, bq1);
    __builtin_amdgcn_s_setprio(0);
    __builtin_amdgcn_s_barrier();
    // mid boundary: A-q1,q3 of tile kt landed; this tile's 4 B loads may fly
    if (st) { asm volatile("s_waitcnt vmcnt(4)" ::: "memory"); }
    else    { asm volatile("s_waitcnt vmcnt(0)" ::: "memory"); }
    __builtin_amdgcn_s_barrier();
    __builtin_amdgcn_sched_barrier(0);
    // phase 2: (mh1, kh0)
    LOADA(1, sc0);
    if (st) { SA(0, kt + 1, nb); SA(2, kt + 1, nb); }
    __builtin_amdgcn_s_barrier();
    asm volatile("s_waitcnt lgkmcnt(0)" ::: "memory");
    __builtin_amdgcn_sched_barrier(0);
    __builtin_amdgcn_s_setprio(1);
    MF(1, bq0);
    __builtin_amdgcn_s_setprio(0);
    __builtin_amdgcn_s_barrier();
    // phase 3: (mh1, kh1)
    LOADA(1, sc1);
    if (st) { SA(1, kt + 1, nb); SA(3, kt + 1, nb); }
    __builtin_amdgcn_s_barrier();
    asm volatile("s_waitcnt lgkmcnt(0)" ::: "memory");
    __builtin_amdgcn_sched_barrier(0);
    __builtin_amdgcn_s_setprio(1);
    MF(1, bq1);
    __builtin_amdgcn_s_setprio(0);
    __builtin_amdgcn_s_barrier();
  }
#undef SA
#undef SB
#undef LOADA
#undef LOADB
#undef MF

  const int region = bx >> 2;  // 0=Q 1=K 2=V, block-uniform
  const float* bias = (region == 0) ? bq : (region == 1) ? bk : bv;
  const float osc = (region == 0) ? qs : 1.0f;
#pragma unroll
  for (int i = 0; i < 8; ++i) {
#pragma unroll
    for (int j = 0; j < 4; ++j) {
      const int n0 = ra0 + wm * 128 + (i >> 2) * 64 + (i & 3) * 16 + lg * 4;
      const int nl = n0 & 1023;
      const int h = nl >> 6, d = nl & 63;
      const int m = rb0 + wn * 64 + j * 16 + lq;
      const int bb = m >> 11, s = m & 2047;
      const float4 b4 = *(const float4*)&bias[nl];
      if (region < 2) {
        u16* out = (region == 0) ? Qb : Kb;
        u16x4 pk;
        pk[0] = f2bf((acc[i][j][0] + b4.x) * osc);
        pk[1] = f2bf((acc[i][j][1] + b4.y) * osc);
        pk[2] = f2bf((acc[i][j][2] + b4.z) * osc);
        pk[3] = f2bf((acc[i][j][3] + b4.w) * osc);
        *(u16x4*)&out[((bb * H_ + h) * S_ + s) * Dh_ + d] = pk;
      } else {
        const float bvv[4] = {b4.x, b4.y, b4.z, b4.w};
#pragma unroll
        for (int r = 0; r < 4; ++r)
          Vtb[((bb * H_ + h) * Dh_ + d + r) * S_ + s] = f2bf(acc[i][j][r] + bvv[r]);
      }
    }
  }
}

// ---------------- proj GEMM, 2-phase dbuf, SINGLE barrier per K-step (R13) ----------------
__global__ __launch_bounds__(256) void proj_gemm(const u16* __restrict__ Am,
                                                 const u16* __restrict__ Bm,
                                                 float* __restrict__ out) {
  __shared__ __align__(16) u16 As[2][4096];
  __shared__ __align__(16) u16 Bs[2][2048];
  const int tid = threadIdx.x;
  const int wv = tid >> 6, ln = tid & 63;
  const int lq = ln & 15, lg = ln >> 4;
  const int bid = blockIdx.x;
  const int xcd = bid & 7, within = bid >> 3;       // 0..63
  const int bx = within & 7;
  const int by = xcd * 8 + (within >> 3);           // 0..63
  const int ra0 = bx * 128, rb0 = by * 64;
  const int wra = wv >> 1, wrb = wv & 1;

  f32x4 acc[4][2];
  const f32x4 z4 = {0.f, 0.f, 0.f, 0.f};
#pragma unroll
  for (int i = 0; i < 4; ++i)
#pragma unroll
    for (int j = 0; j < 2; ++j) acc[i][j] = z4;

  const int arow = tid >> 2;
  const int acol = (tid & 3) * 8;
  const int brow = wv * 16 + (ln >> 2);
  const int bcol = (ln & 3) * 8;
  const u16* Ags = Am + (ra0 + arow) * 1024 + acol;
  const u16* Bgs = Bm + (rb0 + brow) * 1024 + bcol;

#define PSTAGE(KT, BUF) do { const int k0_ = (KT) * 32;              \
    gload16(Ags + k0_,         &As[BUF][wv * 512]);                  \
    gload16(Ags + 65536 + k0_, &As[BUF][wv * 512 + 2048]);           \
    gload16(Bgs + k0_,         &Bs[BUF][wv * 512]); } while (0)

  PSTAGE(0, 0);
  for (int kt = 0; kt < 32; ++kt) {
    const int cb = kt & 1;
    asm volatile("s_waitcnt vmcnt(0)" ::: "memory");
    __builtin_amdgcn_s_barrier();
    __builtin_amdgcn_sched_barrier(0);
    if (kt < 31) PSTAGE(kt + 1, cb ^ 1);
    bf16x8 af[4], bfr[2];
#pragma unroll
    for (int i = 0; i < 4; ++i)
      af[i] = *(const bf16x8*)&As[cb][(wra * 64 + i * 16 + lq) * 32 + lg * 8];
#pragma unroll
    for (int j = 0; j < 2; ++j)
      bfr[j] = *(const bf16x8*)&Bs[cb][(wrb * 32 + j * 16 + lq) * 32 + lg * 8];
    __builtin_amdgcn_s_setprio(1);
#pragma unroll
    for (int i = 0; i < 4; ++i)
#pragma unroll
      for (int j = 0; j < 2; ++j)
        acc[i][j] = __builtin_amdgcn_mfma_f32_16x16x32_bf16(af[i], bfr[j], acc[i][j], 0, 0, 0);
    __builtin_amdgcn_s_setprio(0);
  }
#undef PSTAGE

  const int Ar = ra0 + wra * 64, Br = rb0 + wrb * 32;
#pragma unroll
  for (int i = 0; i < 4; ++i)
#pragma unroll
    for (int j = 0; j < 2; ++j) {
      const int e0 = Ar + i * 16 + lg * 4;
      const int m = Br + j * 16 + lq;
      *(f32x4*)&out[m * 1024 + e0] = acc[i][j];
    }
}

// ---------------- flash attention: 8 waves x 16 q-rows, KVBLK=128, SINGLE barrier/tile (R13) ----
__global__ __launch_bounds__(512, 4) void attn_kernel(const u16* __restrict__ Q,
                                                      const u16* __restrict__ K,
                                                      const u16* __restrict__ Vt,
                                                      u16* __restrict__ Z) {
  __shared__ __align__(16) u16 Ktile[2][8192];   // 128 keys x 64 d, chunk-swizzled (mod-8)
  __shared__ __align__(16) u16 Vtile[2][8192];   // 64 d x 128 keys, chunk-swizzled (mod-16)
  const int tid = threadIdx.x;
  const int wv = tid >> 6, ln = tid & 63;
  const int lq = ln & 15, lg = ln >> 4;
  const bool lgodd = (lg & 1) != 0;
  const int id = blockIdx.x;
  const int within = id >> 3;                      // 0..63
  const int xg = id & 7;                           // XCD group (L2 locality)
  int bh, qt;
  if (within < 32) { bh = xg * 4 + (within >> 4);     qt = 15 - (within & 15); }
  else { const int w = within - 32; bh = xg * 4 + 2 + (w >> 4); qt = w & 15; }
  const int qrow = (qt << 7) + wv * 16 + lq;       // this thread's q row
  const u16* Qp = Q + (size_t)bh * S_ * Dh_;
  const u16* Kp = K + (size_t)bh * S_ * Dh_;
  const u16* Vp = Vt + (size_t)bh * Dh_ * S_;

  // staging: 1024 16B-chunks per tile kind; 512 threads x 2 chunks each
  int kgofs[2], vgrow[2], vgcol[2];
#pragma unroll
  for (int j = 0; j < 2; ++j) {
    const int p = j * 512 + tid;                   // 0..1023 chunk id
    const int gk = p ^ ((p >> 3) & 7);             // K: row=p>>3 (0..127), col swizzled mod 8
    kgofs[j] = (gk >> 3) * 64 + (gk & 7) * 8;
    vgrow[j] = p >> 4;                             // V: row=d (0..63), col swizzled mod 16
    vgcol[j] = ((p & 15) ^ ((p >> 4) & 15)) * 8;
  }
  const int sc0 = (lg ^ (lq & 7)) * 8;             // K read cols (d-half 0)
  const int sc1 = ((4 + lg) ^ (lq & 7)) * 8;       // K read cols (d-half 1)

  bf16x8 qf0 = *(const bf16x8*)&Qp[qrow * Dh_ + lg * 8];
  bf16x8 qf1 = *(const bf16x8*)&Qp[qrow * Dh_ + 32 + lg * 8];

  f32x4 o[4];
  const f32x4 z4 = {0.f, 0.f, 0.f, 0.f};
#pragma unroll
  for (int dt = 0; dt < 4; ++dt) o[dt] = z4;
  float l_lane = 0.f;

#define STAGE(KT, BUF) do { const int kb_ = (KT) * 128;                              \
    gload16(Kp + (size_t)kb_ * 64 + kgofs[0], &Ktile[BUF][wv * 512]);                \
    gload16(Kp + (size_t)kb_ * 64 + kgofs[1], &Ktile[BUF][4096 + wv * 512]);         \
    gload16(Vp + (size_t)vgrow[0] * 2048 + kb_ + vgcol[0], &Vtile[BUF][wv * 512]);   \
    gload16(Vp + (size_t)vgrow[1] * 2048 + kb_ + vgcol[1], &Vtile[BUF][4096 + wv * 512]); \
  } while (0)

  STAGE(0, 0);

  int cur = 0;
  for (int kt = 0; kt <= qt; ++kt) {
    asm volatile("s_waitcnt vmcnt(0)" ::: "memory");   // own stage of tile kt drained
    __builtin_amdgcn_s_barrier();                      // all stages landed; old reads done
    __builtin_amdgcn_sched_barrier(0);
    if (kt < qt) STAGE(kt + 1, cur ^ 1);
    const int k0 = kt * 128;
    const bool diag = (kt == qt);
    const int nkk = diag ? ((wv >> 1) + 1) : 4;    // diag: skip fully-masked 32-key slices
#pragma unroll
    for (int kk = 0; kk < 4; ++kk) {
      if (kk < nkk) {
        const int rA = (kk * 32 + lq) * 64;        // keys kk*32 + 0..15
        const int rB = rA + 1024;                  // +16 keys
        bf16x8 kA0 = *(const bf16x8*)&Ktile[cur][rA + sc0];
        bf16x8 kA1 = *(const bf16x8*)&Ktile[cur][rA + sc1];
        bf16x8 kB0 = *(const bf16x8*)&Ktile[cur][rB + sc0];
        bf16x8 kB1 = *(const bf16x8*)&Ktile[cur][rB + sc1];
        f32x4 sa = z4, sb = z4;
        __builtin_amdgcn_s_setprio(1);
        sa = __builtin_amdgcn_mfma_f32_16x16x32_bf16(kA0, qf0, sa, 0, 0, 0);
        sa = __builtin_amdgcn_mfma_f32_16x16x32_bf16(kA1, qf1, sa, 0, 0, 0);
        sb = __builtin_amdgcn_mfma_f32_16x16x32_bf16(kB0, qf0, sb, 0, 0, 0);
        sb = __builtin_amdgcn_mfma_f32_16x16x32_bf16(kB1, qf1, sb, 0, 0, 0);
        __builtin_amdgcn_s_setprio(0);
        if (diag) {
          const int keyA = k0 + kk * 32 + lg * 4;
          const int keyB = keyA + 16;
#pragma unroll
          for (int r = 0; r < 4; ++r) {
            if (keyA + r > qrow) sa[r] = -3.0e38f;
            if (keyB + r > qrow) sb[r] = -3.0e38f;
          }
        }
        // fixed-max softmax (log2 domain; scores bounded, exp2 can't overflow)
        float e0 = __builtin_amdgcn_exp2f(sa[0]);
        float e1 = __builtin_amdgcn_exp2f(sa[1]);
        float e2 = __builtin_amdgcn_exp2f(sa[2]);
        float e3 = __builtin_amdgcn_exp2f(sa[3]);
        float f0 = __builtin_amdgcn_exp2f(sb[0]);
        float f1 = __builtin_amdgcn_exp2f(sb[1]);
        float f2 = __builtin_amdgcn_exp2f(sb[2]);
        float f3 = __builtin_amdgcn_exp2f(sb[3]);
        l_lane += ((e0 + e1) + (e2 + e3)) + ((f0 + f1) + (f2 + f3));
        u32 A0, A1, B0, B1;
        asm("v_cvt_pk_bf16_f32 %0, %1, %2" : "=v"(A0) : "v"(e0), "v"(e1));
        asm("v_cvt_pk_bf16_f32 %0, %1, %2" : "=v"(A1) : "v"(e2), "v"(e3));
        asm("v_cvt_pk_bf16_f32 %0, %1, %2" : "=v"(B0) : "v"(f0), "v"(f1));
        asm("v_cvt_pk_bf16_f32 %0, %1, %2" : "=v"(B1) : "v"(f2), "v"(f3));
        // in-register P^T routing (verified R6-R13)
        asm("v_permlane32_swap_b32 %0, %1" : "+v"(A0), "+v"(B0));
        asm("v_permlane32_swap_b32 %0, %1" : "+v"(A1), "+v"(B1));
        const u32 A0x = __shfl_xor((int)A0, 16), B0x = __shfl_xor((int)B0, 16);
        const u32 A1x = __shfl_xor((int)A1, 16), B1x = __shfl_xor((int)B1, 16);
        u32x4 w;
        w[0] = lgodd ? B0x : A0;
        w[1] = lgodd ? B1x : A1;
        w[2] = lgodd ? B0 : A0x;
        w[3] = lgodd ? B1 : A1x;
        const bf16x8 pf = __builtin_bit_cast(bf16x8, w);
        const int scvk = ((kk * 4 + lg) ^ lq) * 8;
        __builtin_amdgcn_s_setprio(1);
#pragma unroll
        for (int dt = 0; dt < 4; ++dt) {
          bf16x8 vf = *(const bf16x8*)&Vtile[cur][(dt * 16 + lq) * 128 + scvk];
          o[dt] = __builtin_amdgcn_mfma_f32_16x16x32_bf16(vf, pf, o[dt], 0, 0, 0);
        }
        __builtin_amdgcn_s_setprio(0);
      }
    }
    cur ^= 1;
  }
#undef STAGE

  // epilogue: reduce row-sum across lg groups, apply 1/l and the quirk's extra /8
  float l = l_lane;
  l += __shfl_xor(l, 16);
  l += __shfl_xor(l, 32);
  const float inv = 0.125f / l;
#pragma unroll
  for (int dt = 0; dt < 4; ++dt) {
    u16x4 pko;
#pragma unroll
    for (int r = 0; r < 4; ++r) pko[r] = f2bf(o[dt][r] * inv);
    *(u16x4*)&Z[((size_t)bh * S_ + qrow) * Dh_ + dt * 16 + lg * 4] = pko;
  }
}

extern "C" void kernel_launch(void* const* d_in, const int* in_sizes, int n_in,
                              void* d_out, int out_size, void* d_ws, size_t ws_size,
                              hipStream_t stream) {
  const float* x    = (const float*)d_in[0];
  const float* Wq   = (const float*)d_in[1];
  const float* bq   = (const float*)d_in[2];
  const float* Wk   = (const float*)d_in[3];
  const float* bk   = (const float*)d_in[4];
  const float* Wv   = (const float*)d_in[5];
  const float* bv   = (const float*)d_in[6];
  const float* proj = (const float*)d_in[7];
  float* out = (float*)d_out;

  char* p = (char*)d_ws;
  u16* xb   = (u16*)p; p += (size_t)4096 * 1024 * 2;
  u16* wcat = (u16*)p; p += (size_t)3072 * 1024 * 2;
  u16* pjt  = (u16*)p; p += (size_t)1024 * 1024 * 2;
  u16* Qb   = (u16*)p; p += (size_t)4096 * 1024 * 2;
  u16* Kb   = (u16*)p; p += (size_t)4096 * 1024 * 2;
  u16* Vtb  = (u16*)p; p += (size_t)4096 * 1024 * 2;
  u16* Zb   = (u16*)p; p += (size_t)4096 * 1024 * 2;

  cvt_all<<<dim3(4608), dim3(256), 0, stream>>>(x, Wq, Wk, Wv, proj, xb, wcat, pjt);

  const float qs = 0.125f * 1.44269504f;  // fold score-scale + log2e into Q
  qkv_gemm<<<dim3(192), dim3(512), 0, stream>>>(wcat, xb, bq, bk, bv, Qb, Kb, Vtb, qs);

  attn_kernel<<<dim3(512), dim3(512), 0, stream>>>(Qb, Kb, Vtb, Zb);

  proj_gemm<<<dim3(512), dim3(256), 0, stream>>>(pjt, Zb, out);
}

// Round 15
// 98.707 us; speedup vs baseline: 1.0912x; 1.0256x over previous
//
#include <hip/hip_runtime.h>
#include <hip/hip_bf16.h>

typedef unsigned short u16;
typedef unsigned int u32;
typedef __bf16 bf16x8 __attribute__((ext_vector_type(8)));
typedef float f32x4 __attribute__((ext_vector_type(4)));
typedef u16 u16x8 __attribute__((ext_vector_type(8)));
typedef u16 u16x4 __attribute__((ext_vector_type(4)));
typedef u32 u32x4 __attribute__((ext_vector_type(4)));

#define B_ 2
#define S_ 2048
#define E_ 1024
#define H_ 16
#define Dh_ 64

static __device__ __forceinline__ u16 f2bf(float f) {
  unsigned u = __builtin_bit_cast(unsigned, f);
  u += 0x7fff + ((u >> 16) & 1);   // RNE
  return (u16)(u >> 16);
}

static __device__ __forceinline__ void gload16(const u16* g, u16* l) {
  __builtin_amdgcn_global_load_lds((const __attribute__((address_space(1))) unsigned int*)g,
                                   (__attribute__((address_space(3))) unsigned int*)l,
                                   16, 0, 0);
}

// ---------------- fused fp32 -> bf16 convert: x, Wq|Wk|Wv -> wcat; proj -> projT ----------------
__global__ void cvt_all(const float* __restrict__ x, const float* __restrict__ wq,
                        const float* __restrict__ wk, const float* __restrict__ wv,
                        const float* __restrict__ proj,
                        u16* __restrict__ xb, u16* __restrict__ wcat, u16* __restrict__ pjt) {
  __shared__ float tt[32][33];
  const int bid = blockIdx.x;
  const int tid = threadIdx.x;
  if (bid < 3584) {
    const int i = bid * 256 + tid;                   // 0..917503, exact
    const float* src; u16x8* dst;
    if (i < 524288) {
      src = x + (size_t)i * 8;            dst = (u16x8*)xb + i;
    } else {
      const int j = i - 524288;                      // 0..393215
      dst = (u16x8*)wcat + j;
      if (j < 131072)      src = wq + (size_t)j * 8;
      else if (j < 262144) src = wk + (size_t)(j - 131072) * 8;
      else                 src = wv + (size_t)(j - 262144) * 8;
    }
    float4 a = ((const float4*)src)[0], b = ((const float4*)src)[1];
    u16x8 o;
    o[0] = f2bf(a.x); o[1] = f2bf(a.y); o[2] = f2bf(a.z); o[3] = f2bf(a.w);
    o[4] = f2bf(b.x); o[5] = f2bf(b.y); o[6] = f2bf(b.z); o[7] = f2bf(b.w);
    *dst = o;
  } else {
    const int tb = bid - 3584;                       // 0..1023
    const int e0 = (tb & 31) * 32, f0 = (tb >> 5) * 32;
    const int tx = tid & 31, ty = tid >> 5;          // 32 x 8
#pragma unroll
    for (int r = 0; r < 4; ++r) {
      const int row = ty + r * 8;
      tt[row][tx] = proj[(f0 + row) * 1024 + e0 + tx];
    }
    __syncthreads();
#pragma unroll
    for (int r = 0; r < 4; ++r) {
      const int row = ty + r * 8;
      pjt[(e0 + row) * 1024 + f0 + tx] = f2bf(tt[tx][row]);
    }
  }
}

// ---------------- fused QKV GEMM: 192x256 tile, 8 waves, 4-phase/K-tile, grid 256 (1/CU) -------
// Wcat bf16 [3072][1024] (M), Xm bf16 [4096][1024] (N). 16 x 16 tiles -> 256 blocks, all CUs.
// LDS: A 192x64 (2 buf), B 256x64 (2 buf) = 112 KB. Row-XOR chunk swizzle both sides.
// Per-wave output 96x64: acc[6][4]; phases (mh in {0,1} x kh in {0,1}), 12 MFMA each.
// Boundary: vmcnt(0)+barrier (all 7 stages of tile kt landed); stages of kt+1 spread 2/2/2/1.
__global__ __launch_bounds__(512, 2) void qkv_gemm(const u16* __restrict__ Wcat,
                                                   const u16* __restrict__ Xm,
                                                   const float* __restrict__ bq,
                                                   const float* __restrict__ bk,
                                                   const float* __restrict__ bv,
                                                   u16* __restrict__ Qb, u16* __restrict__ Kb,
                                                   u16* __restrict__ Vtb, float qs) {
  __shared__ __align__(16) u16 Alds[2][12288];   // 192 rows x 64 k
  __shared__ __align__(16) u16 Blds[2][16384];   // 256 rows x 64 k
  const int tid = threadIdx.x;                   // 0..511
  const int wv = tid >> 6, ln = tid & 63;
  const int lq = ln & 15, lg = ln >> 4;
  const int wm = wv >> 2, wn = wv & 3;           // wave grid 2(M) x 4(N)
  const int bid = blockIdx.x;
  const int xcd = bid & 7, w = bid >> 3;         // w 0..31
  const int bx = w & 15;                         // 0..15 (M tiles of 192)
  const int by = xcd * 2 + (w >> 4);             // 0..15 (N tiles of 256)
  const int ra0 = bx * 192, rb0 = by * 256;

  // staging: thread t stages LDS chunk G*512+t; source col pre-swizzled (c ^ row&7)
  const int r_t = tid >> 3, c_t = tid & 7;       // row-in-group 0..63, chunk 0..7
  const int gcol = (c_t ^ (r_t & 7)) * 8;        // swizzled source k-offset (u16)
  const u16* Asrc = Wcat + (ra0 + r_t) * 1024 + gcol;
  const u16* Bsrc = Xm   + (rb0 + r_t) * 1024 + gcol;

  // fragment read offsets (swizzled): chunk pos = (kh*4+lg) ^ (lq&7)
  const int sc0 = (lg ^ (lq & 7)) * 8;
  const int sc1 = ((4 + lg) ^ (lq & 7)) * 8;
  const int baseA = (wm * 96 + lq) * 64;         // + mh*3072 + ii*1024 + sc
  const int baseB = (wn * 64 + lq) * 64;         // + j*1024 + sc

  f32x4 acc[6][4];
  const f32x4 z4 = {0.f, 0.f, 0.f, 0.f};
#pragma unroll
  for (int i = 0; i < 6; ++i)
#pragma unroll
    for (int j = 0; j < 4; ++j) acc[i][j] = z4;

#define SA(G, KT, BUF) gload16(Asrc + (G) * 65536 + (KT) * 64, &Alds[BUF][((G) * 512 + tid) * 8])
#define SB(G, KT, BUF) gload16(Bsrc + (G) * 65536 + (KT) * 64, &Blds[BUF][((G) * 512 + tid) * 8])
#define LOADA(MH, SC) do {                                                         \
    _Pragma("unroll") for (int ii = 0; ii < 3; ++ii)                               \
      af[ii] = *(const bf16x8*)&Alds[cb][baseA + (MH) * 3072 + ii * 1024 + (SC)];  \
  } while (0)
#define LOADB(DST, SC) do {                                                        \
    _Pragma("unroll") for (int j = 0; j < 4; ++j)                                  \
      DST[j] = *(const bf16x8*)&Blds[cb][baseB + j * 1024 + (SC)];                 \
  } while (0)
#define MF(MH, BQ) do {                                                            \
    _Pragma("unroll") for (int ii = 0; ii < 3; ++ii)                               \
      _Pragma("unroll") for (int j = 0; j < 4; ++j)                                \
        acc[(MH) * 3 + ii][j] =                                                    \
            __builtin_amdgcn_mfma_f32_16x16x32_bf16(af[ii], BQ[j],                 \
                                                    acc[(MH) * 3 + ii][j], 0, 0, 0); \
  } while (0)

  // prologue: stage tile 0 (7 loads/thread)
  SB(0, 0, 0); SB(1, 0, 0); SB(2, 0, 0); SB(3, 0, 0);
  SA(0, 0, 0); SA(1, 0, 0); SA(2, 0, 0);

  for (int kt = 0; kt < 16; ++kt) {
    const int cb = kt & 1, nb = cb ^ 1;
    const bool st = (kt < 15);
    asm volatile("s_waitcnt vmcnt(0)" ::: "memory");   // all stages of tile kt landed
    __builtin_amdgcn_s_barrier();
    __builtin_amdgcn_sched_barrier(0);
    bf16x8 af[3], bq0[4], bq1[4];
    // phase 0: (mh0, kh0)
    LOADA(0, sc0);
    LOADB(bq0, sc0);
    if (st) { SB(0, kt + 1, nb); SB(1, kt + 1, nb); }
    __builtin_amdgcn_s_barrier();
    asm volatile("s_waitcnt lgkmcnt(0)" ::: "memory");
    __builtin_amdgcn_sched_barrier(0);
    __builtin_amdgcn_s_setprio(1);
    MF(0, bq0);
    __builtin_amdgcn_s_setprio(0);
    __builtin_amdgcn_s_barrier();
    // phase 1: (mh0, kh1)
    LOADA(0, sc1);
    LOADB(bq1, sc1);
    if (st) { SB(2, kt + 1, nb); SB(3, kt + 1, nb); }
    __builtin_amdgcn_s_barrier();
    asm volatile("s_waitcnt lgkmcnt(0)" ::: "memory");
    __builtin_amdgcn_sched_barrier(0);
    __builtin_amdgcn_s_setprio(1);
    MF(0, bq1);
    __builtin_amdgcn_s_setprio(0);
    __builtin_amdgcn_s_barrier();
    // phase 2: (mh1, kh0)
    LOADA(1, sc0);
    if (st) { SA(0, kt + 1, nb); SA(1, kt + 1, nb); }
    __builtin_amdgcn_s_barrier();
    asm volatile("s_waitcnt lgkmcnt(0)" ::: "memory");
    __builtin_amdgcn_sched_barrier(0);
    __builtin_amdgcn_s_setprio(1);
    MF(1, bq0);
    __builtin_amdgcn_s_setprio(0);
    __builtin_amdgcn_s_barrier();
    // phase 3: (mh1, kh1)
    LOADA(1, sc1);
    if (st) { SA(2, kt + 1, nb); }
    __builtin_amdgcn_s_barrier();
    asm volatile("s_waitcnt lgkmcnt(0)" ::: "memory");
    __builtin_amdgcn_sched_barrier(0);
    __builtin_amdgcn_s_setprio(1);
    MF(1, bq1);
    __builtin_amdgcn_s_setprio(0);
    __builtin_amdgcn_s_barrier();
  }
#undef SA
#undef SB
#undef LOADA
#undef LOADB
#undef MF

  // epilogue: region per fragment (16-row frags never straddle a 1024 boundary)
#pragma unroll
  for (int i = 0; i < 6; ++i) {
    const int n0 = ra0 + wm * 96 + i * 16 + lg * 4;
    const int reg_i = n0 >> 10;                  // 0=Q 1=K 2=V, wave-uniform per frag
    const int nl = n0 & 1023;
    const int h = nl >> 6, d = nl & 63;
    const float* bias = (reg_i == 0) ? bq : (reg_i == 1) ? bk : bv;
    const float osc = (reg_i == 0) ? qs : 1.0f;
    const float4 b4 = *(const float4*)&bias[nl];
#pragma unroll
    for (int j = 0; j < 4; ++j) {
      const int m = rb0 + wn * 64 + j * 16 + lq;
      const int bb = m >> 11, s = m & 2047;
      if (reg_i < 2) {
        u16* out = (reg_i == 0) ? Qb : Kb;
        u16x4 pk;
        pk[0] = f2bf((acc[i][j][0] + b4.x) * osc);
        pk[1] = f2bf((acc[i][j][1] + b4.y) * osc);
        pk[2] = f2bf((acc[i][j][2] + b4.z) * osc);
        pk[3] = f2bf((acc[i][j][3] + b4.w) * osc);
        *(u16x4*)&out[((bb * H_ + h) * S_ + s) * Dh_ + d] = pk;
      } else {
        const float bvv[4] = {b4.x, b4.y, b4.z, b4.w};
#pragma unroll
        for (int r = 0; r < 4; ++r)
          Vtb[((bb * H_ + h) * Dh_ + d + r) * S_ + s] = f2bf(acc[i][j][r] + bvv[r]);
      }
    }
  }
}

// ---------------- proj GEMM, 2-phase dbuf, SINGLE barrier per K-step (R13) ----------------
__global__ __launch_bounds__(256) void proj_gemm(const u16* __restrict__ Am,
                                                 const u16* __restrict__ Bm,
                                                 float* __restrict__ out) {
  __shared__ __align__(16) u16 As[2][4096];
  __shared__ __align__(16) u16 Bs[2][2048];
  const int tid = threadIdx.x;
  const int wv = tid >> 6, ln = tid & 63;
  const int lq = ln & 15, lg = ln >> 4;
  const int bid = blockIdx.x;
  const int xcd = bid & 7, within = bid >> 3;       // 0..63
  const int bx = within & 7;
  const int by = xcd * 8 + (within >> 3);           // 0..63
  const int ra0 = bx * 128, rb0 = by * 64;
  const int wra = wv >> 1, wrb = wv & 1;

  f32x4 acc[4][2];
  const f32x4 z4 = {0.f, 0.f, 0.f, 0.f};
#pragma unroll
  for (int i = 0; i < 4; ++i)
#pragma unroll
    for (int j = 0; j < 2; ++j) acc[i][j] = z4;

  const int arow = tid >> 2;
  const int acol = (tid & 3) * 8;
  const int brow = wv * 16 + (ln >> 2);
  const int bcol = (ln & 3) * 8;
  const u16* Ags = Am + (ra0 + arow) * 1024 + acol;
  const u16* Bgs = Bm + (rb0 + brow) * 1024 + bcol;

#define PSTAGE(KT, BUF) do { const int k0_ = (KT) * 32;              \
    gload16(Ags + k0_,         &As[BUF][wv * 512]);                  \
    gload16(Ags + 65536 + k0_, &As[BUF][wv * 512 + 2048]);           \
    gload16(Bgs + k0_,         &Bs[BUF][wv * 512]); } while (0)

  PSTAGE(0, 0);
  for (int kt = 0; kt < 32; ++kt) {
    const int cb = kt & 1;
    asm volatile("s_waitcnt vmcnt(0)" ::: "memory");
    __builtin_amdgcn_s_barrier();
    __builtin_amdgcn_sched_barrier(0);
    if (kt < 31) PSTAGE(kt + 1, cb ^ 1);
    bf16x8 af[4], bfr[2];
#pragma unroll
    for (int i = 0; i < 4; ++i)
      af[i] = *(const bf16x8*)&As[cb][(wra * 64 + i * 16 + lq) * 32 + lg * 8];
#pragma unroll
    for (int j = 0; j < 2; ++j)
      bfr[j] = *(const bf16x8*)&Bs[cb][(wrb * 32 + j * 16 + lq) * 32 + lg * 8];
    __builtin_amdgcn_s_setprio(1);
#pragma unroll
    for (int i = 0; i < 4; ++i)
#pragma unroll
      for (int j = 0; j < 2; ++j)
        acc[i][j] = __builtin_amdgcn_mfma_f32_16x16x32_bf16(af[i], bfr[j], acc[i][j], 0, 0, 0);
    __builtin_amdgcn_s_setprio(0);
  }
#undef PSTAGE

  const int Ar = ra0 + wra * 64, Br = rb0 + wrb * 32;
#pragma unroll
  for (int i = 0; i < 4; ++i)
#pragma unroll
    for (int j = 0; j < 2; ++j) {
      const int e0 = Ar + i * 16 + lg * 4;
      const int m = Br + j * 16 + lq;
      *(f32x4*)&out[m * 1024 + e0] = acc[i][j];
    }
}

// ---------------- flash attention: 8 waves x 16 q-rows, KVBLK=128, SINGLE barrier/tile (R13) ----
__global__ __launch_bounds__(512, 4) void attn_kernel(const u16* __restrict__ Q,
                                                      const u16* __restrict__ K,
                                                      const u16* __restrict__ Vt,
                                                      u16* __restrict__ Z) {
  __shared__ __align__(16) u16 Ktile[2][8192];   // 128 keys x 64 d, chunk-swizzled (mod-8)
  __shared__ __align__(16) u16 Vtile[2][8192];   // 64 d x 128 keys, chunk-swizzled (mod-16)
  const int tid = threadIdx.x;
  const int wv = tid >> 6, ln = tid & 63;
  const int lq = ln & 15, lg = ln >> 4;
  const bool lgodd = (lg & 1) != 0;
  const int id = blockIdx.x;
  const int within = id >> 3;                      // 0..63
  const int xg = id & 7;                           // XCD group (L2 locality)
  int bh, qt;
  if (within < 32) { bh = xg * 4 + (within >> 4);     qt = 15 - (within & 15); }
  else { const int w = within - 32; bh = xg * 4 + 2 + (w >> 4); qt = w & 15; }
  const int qrow = (qt << 7) + wv * 16 + lq;       // this thread's q row
  const u16* Qp = Q + (size_t)bh * S_ * Dh_;
  const u16* Kp = K + (size_t)bh * S_ * Dh_;
  const u16* Vp = Vt + (size_t)bh * Dh_ * S_;

  // staging: 1024 16B-chunks per tile kind; 512 threads x 2 chunks each
  int kgofs[2], vgrow[2], vgcol[2];
#pragma unroll
  for (int j = 0; j < 2; ++j) {
    const int p = j * 512 + tid;                   // 0..1023 chunk id
    const int gk = p ^ ((p >> 3) & 7);             // K: row=p>>3 (0..127), col swizzled mod 8
    kgofs[j] = (gk >> 3) * 64 + (gk & 7) * 8;
    vgrow[j] = p >> 4;                             // V: row=d (0..63), col swizzled mod 16
    vgcol[j] = ((p & 15) ^ ((p >> 4) & 15)) * 8;
  }
  const int sc0 = (lg ^ (lq & 7)) * 8;             // K read cols (d-half 0)
  const int sc1 = ((4 + lg) ^ (lq & 7)) * 8;       // K read cols (d-half 1)

  bf16x8 qf0 = *(const bf16x8*)&Qp[qrow * Dh_ + lg * 8];
  bf16x8 qf1 = *(const bf16x8*)&Qp[qrow * Dh_ + 32 + lg * 8];

  f32x4 o[4];
  const f32x4 z4 = {0.f, 0.f, 0.f, 0.f};
#pragma unroll
  for (int dt = 0; dt < 4; ++dt) o[dt] = z4;
  float l_lane = 0.f;

#define STAGE(KT, BUF) do { const int kb_ = (KT) * 128;                              \
    gload16(Kp + (size_t)kb_ * 64 + kgofs[0], &Ktile[BUF][wv * 512]);                \
    gload16(Kp + (size_t)kb_ * 64 + kgofs[1], &Ktile[BUF][4096 + wv * 512]);         \
    gload16(Vp + (size_t)vgrow[0] * 2048 + kb_ + vgcol[0], &Vtile[BUF][wv * 512]);   \
    gload16(Vp + (size_t)vgrow[1] * 2048 + kb_ + vgcol[1], &Vtile[BUF][4096 + wv * 512]); \
  } while (0)

  STAGE(0, 0);

  int cur = 0;
  for (int kt = 0; kt <= qt; ++kt) {
    asm volatile("s_waitcnt vmcnt(0)" ::: "memory");   // own stage of tile kt drained
    __builtin_amdgcn_s_barrier();                      // all stages landed; old reads done
    __builtin_amdgcn_sched_barrier(0);
    if (kt < qt) STAGE(kt + 1, cur ^ 1);
    const int k0 = kt * 128;
    const bool diag = (kt == qt);
    const int nkk = diag ? ((wv >> 1) + 1) : 4;    // diag: skip fully-masked 32-key slices
#pragma unroll
    for (int kk = 0; kk < 4; ++kk) {
      if (kk < nkk) {
        const int rA = (kk * 32 + lq) * 64;        // keys kk*32 + 0..15
        const int rB = rA + 1024;                  // +16 keys
        bf16x8 kA0 = *(const bf16x8*)&Ktile[cur][rA + sc0];
        bf16x8 kA1 = *(const bf16x8*)&Ktile[cur][rA + sc1];
        bf16x8 kB0 = *(const bf16x8*)&Ktile[cur][rB + sc0];
        bf16x8 kB1 = *(const bf16x8*)&Ktile[cur][rB + sc1];
        f32x4 sa = z4, sb = z4;
        __builtin_amdgcn_s_setprio(1);
        sa = __builtin_amdgcn_mfma_f32_16x16x32_bf16(kA0, qf0, sa, 0, 0, 0);
        sa = __builtin_amdgcn_mfma_f32_16x16x32_bf16(kA1, qf1, sa, 0, 0, 0);
        sb = __builtin_amdgcn_mfma_f32_16x16x32_bf16(kB0, qf0, sb, 0, 0, 0);
        sb = __builtin_amdgcn_mfma_f32_16x16x32_bf16(kB1, qf1, sb, 0, 0, 0);
        __builtin_amdgcn_s_setprio(0);
        if (diag) {
          const int keyA = k0 + kk * 32 + lg * 4;
          const int keyB = keyA + 16;
#pragma unroll
          for (int r = 0; r < 4; ++r) {
            if (keyA + r > qrow) sa[r] = -3.0e38f;
            if (keyB + r > qrow) sb[r] = -3.0e38f;
          }
        }
        // fixed-max softmax (log2 domain; scores bounded, exp2 can't overflow)
        float e0 = __builtin_amdgcn_exp2f(sa[0]);
        float e1 = __builtin_amdgcn_exp2f(sa[1]);
        float e2 = __builtin_amdgcn_exp2f(sa[2]);
        float e3 = __builtin_amdgcn_exp2f(sa[3]);
        float f0 = __builtin_amdgcn_exp2f(sb[0]);
        float f1 = __builtin_amdgcn_exp2f(sb[1]);
        float f2 = __builtin_amdgcn_exp2f(sb[2]);
        float f3 = __builtin_amdgcn_exp2f(sb[3]);
        l_lane += ((e0 + e1) + (e2 + e3)) + ((f0 + f1) + (f2 + f3));
        u32 A0, A1, B0, B1;
        asm("v_cvt_pk_bf16_f32 %0, %1, %2" : "=v"(A0) : "v"(e0), "v"(e1));
        asm("v_cvt_pk_bf16_f32 %0, %1, %2" : "=v"(A1) : "v"(e2), "v"(e3));
        asm("v_cvt_pk_bf16_f32 %0, %1, %2" : "=v"(B0) : "v"(f0), "v"(f1));
        asm("v_cvt_pk_bf16_f32 %0, %1, %2" : "=v"(B1) : "v"(f2), "v"(f3));
        // in-register P^T routing (verified R6-R14)
        asm("v_permlane32_swap_b32 %0, %1" : "+v"(A0), "+v"(B0));
        asm("v_permlane32_swap_b32 %0, %1" : "+v"(A1), "+v"(B1));
        const u32 A0x = __shfl_xor((int)A0, 16), B0x = __shfl_xor((int)B0, 16);
        const u32 A1x = __shfl_xor((int)A1, 16), B1x = __shfl_xor((int)B1, 16);
        u32x4 w;
        w[0] = lgodd ? B0x : A0;
        w[1] = lgodd ? B1x : A1;
        w[2] = lgodd ? B0 : A0x;
        w[3] = lgodd ? B1 : A1x;
        const bf16x8 pf = __builtin_bit_cast(bf16x8, w);
        const int scvk = ((kk * 4 + lg) ^ lq) * 8;
        __builtin_amdgcn_s_setprio(1);
#pragma unroll
        for (int dt = 0; dt < 4; ++dt) {
          bf16x8 vf = *(const bf16x8*)&Vtile[cur][(dt * 16 + lq) * 128 + scvk];
          o[dt] = __builtin_amdgcn_mfma_f32_16x16x32_bf16(vf, pf, o[dt], 0, 0, 0);
        }
        __builtin_amdgcn_s_setprio(0);
      }
    }
    cur ^= 1;
  }
#undef STAGE

  // epilogue: reduce row-sum across lg groups, apply 1/l and the quirk's extra /8
  float l = l_lane;
  l += __shfl_xor(l, 16);
  l += __shfl_xor(l, 32);
  const float inv = 0.125f / l;
#pragma unroll
  for (int dt = 0; dt < 4; ++dt) {
    u16x4 pko;
#pragma unroll
    for (int r = 0; r < 4; ++r) pko[r] = f2bf(o[dt][r] * inv);
    *(u16x4*)&Z[((size_t)bh * S_ + qrow) * Dh_ + dt * 16 + lg * 4] = pko;
  }
}

extern "C" void kernel_launch(void* const* d_in, const int* in_sizes, int n_in,
                              void* d_out, int out_size, void* d_ws, size_t ws_size,
                              hipStream_t stream) {
  const float* x    = (const float*)d_in[0];
  const float* Wq   = (const float*)d_in[1];
  const float* bq   = (const float*)d_in[2];
  const float* Wk   = (const float*)d_in[3];
  const float* bk   = (const float*)d_in[4];
  const float* Wv   = (const float*)d_in[5];
  const float* bv   = (const float*)d_in[6];
  const float* proj = (const float*)d_in[7];
  float* out = (float*)d_out;

  char* p = (char*)d_ws;
  u16* xb   = (u16*)p; p += (size_t)4096 * 1024 * 2;
  u16* wcat = (u16*)p; p += (size_t)3072 * 1024 * 2;
  u16* pjt  = (u16*)p; p += (size_t)1024 * 1024 * 2;
  u16* Qb   = (u16*)p; p += (size_t)4096 * 1024 * 2;
  u16* Kb   = (u16*)p; p += (size_t)4096 * 1024 * 2;
  u16* Vtb  = (u16*)p; p += (size_t)4096 * 1024 * 2;
  u16* Zb   = (u16*)p; p += (size_t)4096 * 1024 * 2;

  cvt_all<<<dim3(4608), dim3(256), 0, stream>>>(x, Wq, Wk, Wv, proj, xb, wcat, pjt);

  const float qs = 0.125f * 1.44269504f;  // fold score-scale + log2e into Q
  qkv_gemm<<<dim3(256), dim3(512), 0, stream>>>(wcat, xb, bq, bk, bv, Qb, Kb, Vtb, qs);

  attn_kernel<<<dim3(512), dim3(512), 0, stream>>>(Qb, Kb, Vtb, Zb);

  proj_gemm<<<dim3(512), dim3(256), 0, stream>>>(pjt, Zb, out);
}

// Round 16
// 98.673 us; speedup vs baseline: 1.0916x; 1.0003x over previous
//
#include <hip/hip_runtime.h>
#include <hip/hip_bf16.h>

typedef unsigned short u16;
typedef unsigned int u32;
typedef __bf16 bf16x8 __attribute__((ext_vector_type(8)));
typedef float f32x4 __attribute__((ext_vector_type(4)));
typedef u16 u16x8 __attribute__((ext_vector_type(8)));
typedef u16 u16x4 __attribute__((ext_vector_type(4)));
typedef u32 u32x4 __attribute__((ext_vector_type(4)));

#define B_ 2
#define S_ 2048
#define E_ 1024
#define H_ 16
#define Dh_ 64

static __device__ __forceinline__ u16 f2bf(float f) {
  unsigned u = __builtin_bit_cast(unsigned, f);
  u += 0x7fff + ((u >> 16) & 1);   // RNE
  return (u16)(u >> 16);
}

static __device__ __forceinline__ void gload16(const u16* g, u16* l) {
  __builtin_amdgcn_global_load_lds((const __attribute__((address_space(1))) unsigned int*)g,
                                   (__attribute__((address_space(3))) unsigned int*)l,
                                   16, 0, 0);
}

// ---------------- fused fp32 -> bf16 convert: x, Wq|Wk|Wv -> wcat; proj -> projT ----------------
__global__ void cvt_all(const float* __restrict__ x, const float* __restrict__ wq,
                        const float* __restrict__ wk, const float* __restrict__ wv,
                        const float* __restrict__ proj,
                        u16* __restrict__ xb, u16* __restrict__ wcat, u16* __restrict__ pjt) {
  __shared__ float tt[32][33];
  const int bid = blockIdx.x;
  const int tid = threadIdx.x;
  if (bid < 3584) {
    const int i = bid * 256 + tid;                   // 0..917503, exact
    const float* src; u16x8* dst;
    if (i < 524288) {
      src = x + (size_t)i * 8;            dst = (u16x8*)xb + i;
    } else {
      const int j = i - 524288;                      // 0..393215
      dst = (u16x8*)wcat + j;
      if (j < 131072)      src = wq + (size_t)j * 8;
      else if (j < 262144) src = wk + (size_t)(j - 131072) * 8;
      else                 src = wv + (size_t)(j - 262144) * 8;
    }
    float4 a = ((const float4*)src)[0], b = ((const float4*)src)[1];
    u16x8 o;
    o[0] = f2bf(a.x); o[1] = f2bf(a.y); o[2] = f2bf(a.z); o[3] = f2bf(a.w);
    o[4] = f2bf(b.x); o[5] = f2bf(b.y); o[6] = f2bf(b.z); o[7] = f2bf(b.w);
    *dst = o;
  } else {
    const int tb = bid - 3584;                       // 0..1023
    const int e0 = (tb & 31) * 32, f0 = (tb >> 5) * 32;
    const int tx = tid & 31, ty = tid >> 5;          // 32 x 8
#pragma unroll
    for (int r = 0; r < 4; ++r) {
      const int row = ty + r * 8;
      tt[row][tx] = proj[(f0 + row) * 1024 + e0 + tx];
    }
    __syncthreads();
#pragma unroll
    for (int r = 0; r < 4; ++r) {
      const int row = ty + r * 8;
      pjt[(e0 + row) * 1024 + f0 + tx] = f2bf(tt[tx][row]);
    }
  }
}

// ---------------- fused QKV GEMM: 192x256 tile, 8 waves, 4-phase/K-tile, grid 256 (R15) -------
__global__ __launch_bounds__(512, 2) void qkv_gemm(const u16* __restrict__ Wcat,
                                                   const u16* __restrict__ Xm,
                                                   const float* __restrict__ bq,
                                                   const float* __restrict__ bk,
                                                   const float* __restrict__ bv,
                                                   u16* __restrict__ Qb, u16* __restrict__ Kb,
                                                   u16* __restrict__ Vtb, float qs) {
  __shared__ __align__(16) u16 Alds[2][12288];   // 192 rows x 64 k
  __shared__ __align__(16) u16 Blds[2][16384];   // 256 rows x 64 k
  const int tid = threadIdx.x;                   // 0..511
  const int wv = tid >> 6, ln = tid & 63;
  const int lq = ln & 15, lg = ln >> 4;
  const int wm = wv >> 2, wn = wv & 3;           // wave grid 2(M) x 4(N)
  const int bid = blockIdx.x;
  const int xcd = bid & 7, w = bid >> 3;         // w 0..31
  const int bx = w & 15;                         // 0..15 (M tiles of 192)
  const int by = xcd * 2 + (w >> 4);             // 0..15 (N tiles of 256)
  const int ra0 = bx * 192, rb0 = by * 256;

  // staging: thread t stages LDS chunk G*512+t; source col pre-swizzled (c ^ row&7)
  const int r_t = tid >> 3, c_t = tid & 7;       // row-in-group 0..63, chunk 0..7
  const int gcol = (c_t ^ (r_t & 7)) * 8;        // swizzled source k-offset (u16)
  const u16* Asrc = Wcat + (ra0 + r_t) * 1024 + gcol;
  const u16* Bsrc = Xm   + (rb0 + r_t) * 1024 + gcol;

  // fragment read offsets (swizzled): chunk pos = (kh*4+lg) ^ (lq&7)
  const int sc0 = (lg ^ (lq & 7)) * 8;
  const int sc1 = ((4 + lg) ^ (lq & 7)) * 8;
  const int baseA = (wm * 96 + lq) * 64;         // + mh*3072 + ii*1024 + sc
  const int baseB = (wn * 64 + lq) * 64;         // + j*1024 + sc

  f32x4 acc[6][4];
  const f32x4 z4 = {0.f, 0.f, 0.f, 0.f};
#pragma unroll
  for (int i = 0; i < 6; ++i)
#pragma unroll
    for (int j = 0; j < 4; ++j) acc[i][j] = z4;

#define SA(G, KT, BUF) gload16(Asrc + (G) * 65536 + (KT) * 64, &Alds[BUF][((G) * 512 + tid) * 8])
#define SB(G, KT, BUF) gload16(Bsrc + (G) * 65536 + (KT) * 64, &Blds[BUF][((G) * 512 + tid) * 8])
#define LOADA(MH, SC) do {                                                         \
    _Pragma("unroll") for (int ii = 0; ii < 3; ++ii)                               \
      af[ii] = *(const bf16x8*)&Alds[cb][baseA + (MH) * 3072 + ii * 1024 + (SC)];  \
  } while (0)
#define LOADB(DST, SC) do {                                                        \
    _Pragma("unroll") for (int j = 0; j < 4; ++j)                                  \
      DST[j] = *(const bf16x8*)&Blds[cb][baseB + j * 1024 + (SC)];                 \
  } while (0)
#define MF(MH, BQ) do {                                                            \
    _Pragma("unroll") for (int ii = 0; ii < 3; ++ii)                               \
      _Pragma("unroll") for (int j = 0; j < 4; ++j)                                \
        acc[(MH) * 3 + ii][j] =                                                    \
            __builtin_amdgcn_mfma_f32_16x16x32_bf16(af[ii], BQ[j],                 \
                                                    acc[(MH) * 3 + ii][j], 0, 0, 0); \
  } while (0)

  // prologue: stage tile 0 (7 loads/thread)
  SB(0, 0, 0); SB(1, 0, 0); SB(2, 0, 0); SB(3, 0, 0);
  SA(0, 0, 0); SA(1, 0, 0); SA(2, 0, 0);

  for (int kt = 0; kt < 16; ++kt) {
    const int cb = kt & 1, nb = cb ^ 1;
    const bool st = (kt < 15);
    asm volatile("s_waitcnt vmcnt(0)" ::: "memory");   // all stages of tile kt landed
    __builtin_amdgcn_s_barrier();
    __builtin_amdgcn_sched_barrier(0);
    bf16x8 af[3], bq0[4], bq1[4];
    // phase 0: (mh0, kh0)
    LOADA(0, sc0);
    LOADB(bq0, sc0);
    if (st) { SB(0, kt + 1, nb); SB(1, kt + 1, nb); }
    __builtin_amdgcn_s_barrier();
    asm volatile("s_waitcnt lgkmcnt(0)" ::: "memory");
    __builtin_amdgcn_sched_barrier(0);
    __builtin_amdgcn_s_setprio(1);
    MF(0, bq0);
    __builtin_amdgcn_s_setprio(0);
    __builtin_amdgcn_s_barrier();
    // phase 1: (mh0, kh1)
    LOADA(0, sc1);
    LOADB(bq1, sc1);
    if (st) { SB(2, kt + 1, nb); SB(3, kt + 1, nb); }
    __builtin_amdgcn_s_barrier();
    asm volatile("s_waitcnt lgkmcnt(0)" ::: "memory");
    __builtin_amdgcn_sched_barrier(0);
    __builtin_amdgcn_s_setprio(1);
    MF(0, bq1);
    __builtin_amdgcn_s_setprio(0);
    __builtin_amdgcn_s_barrier();
    // phase 2: (mh1, kh0)
    LOADA(1, sc0);
    if (st) { SA(0, kt + 1, nb); SA(1, kt + 1, nb); }
    __builtin_amdgcn_s_barrier();
    asm volatile("s_waitcnt lgkmcnt(0)" ::: "memory");
    __builtin_amdgcn_sched_barrier(0);
    __builtin_amdgcn_s_setprio(1);
    MF(1, bq0);
    __builtin_amdgcn_s_setprio(0);
    __builtin_amdgcn_s_barrier();
    // phase 3: (mh1, kh1)
    LOADA(1, sc1);
    if (st) { SA(2, kt + 1, nb); }
    __builtin_amdgcn_s_barrier();
    asm volatile("s_waitcnt lgkmcnt(0)" ::: "memory");
    __builtin_amdgcn_sched_barrier(0);
    __builtin_amdgcn_s_setprio(1);
    MF(1, bq1);
    __builtin_amdgcn_s_setprio(0);
    __builtin_amdgcn_s_barrier();
  }
#undef SA
#undef SB
#undef LOADA
#undef LOADB
#undef MF

  // epilogue: region per fragment (16-row frags never straddle a 1024 boundary)
#pragma unroll
  for (int i = 0; i < 6; ++i) {
    const int n0 = ra0 + wm * 96 + i * 16 + lg * 4;
    const int reg_i = n0 >> 10;                  // 0=Q 1=K 2=V, wave-uniform per frag
    const int nl = n0 & 1023;
    const int h = nl >> 6, d = nl & 63;
    const float* bias = (reg_i == 0) ? bq : (reg_i == 1) ? bk : bv;
    const float osc = (reg_i == 0) ? qs : 1.0f;
    const float4 b4 = *(const float4*)&bias[nl];
#pragma unroll
    for (int j = 0; j < 4; ++j) {
      const int m = rb0 + wn * 64 + j * 16 + lq;
      const int bb = m >> 11, s = m & 2047;
      if (reg_i < 2) {
        u16* out = (reg_i == 0) ? Qb : Kb;
        u16x4 pk;
        pk[0] = f2bf((acc[i][j][0] + b4.x) * osc);
        pk[1] = f2bf((acc[i][j][1] + b4.y) * osc);
        pk[2] = f2bf((acc[i][j][2] + b4.z) * osc);
        pk[3] = f2bf((acc[i][j][3] + b4.w) * osc);
        *(u16x4*)&out[((bb * H_ + h) * S_ + s) * Dh_ + d] = pk;
      } else {
        const float bvv[4] = {b4.x, b4.y, b4.z, b4.w};
#pragma unroll
        for (int r = 0; r < 4; ++r)
          Vtb[((bb * H_ + h) * Dh_ + d + r) * S_ + s] = f2bf(acc[i][j][r] + bvv[r]);
      }
    }
  }
}

// ---------------- proj GEMM, 2-phase dbuf, SINGLE barrier per K-step (R13) ----------------
__global__ __launch_bounds__(256) void proj_gemm(const u16* __restrict__ Am,
                                                 const u16* __restrict__ Bm,
                                                 float* __restrict__ out) {
  __shared__ __align__(16) u16 As[2][4096];
  __shared__ __align__(16) u16 Bs[2][2048];
  const int tid = threadIdx.x;
  const int wv = tid >> 6, ln = tid & 63;
  const int lq = ln & 15, lg = ln >> 4;
  const int bid = blockIdx.x;
  const int xcd = bid & 7, within = bid >> 3;       // 0..63
  const int bx = within & 7;
  const int by = xcd * 8 + (within >> 3);           // 0..63
  const int ra0 = bx * 128, rb0 = by * 64;
  const int wra = wv >> 1, wrb = wv & 1;

  f32x4 acc[4][2];
  const f32x4 z4 = {0.f, 0.f, 0.f, 0.f};
#pragma unroll
  for (int i = 0; i < 4; ++i)
#pragma unroll
    for (int j = 0; j < 2; ++j) acc[i][j] = z4;

  const int arow = tid >> 2;
  const int acol = (tid & 3) * 8;
  const int brow = wv * 16 + (ln >> 2);
  const int bcol = (ln & 3) * 8;
  const u16* Ags = Am + (ra0 + arow) * 1024 + acol;
  const u16* Bgs = Bm + (rb0 + brow) * 1024 + bcol;

#define PSTAGE(KT, BUF) do { const int k0_ = (KT) * 32;              \
    gload16(Ags + k0_,         &As[BUF][wv * 512]);                  \
    gload16(Ags + 65536 + k0_, &As[BUF][wv * 512 + 2048]);           \
    gload16(Bgs + k0_,         &Bs[BUF][wv * 512]); } while (0)

  PSTAGE(0, 0);
  for (int kt = 0; kt < 32; ++kt) {
    const int cb = kt & 1;
    asm volatile("s_waitcnt vmcnt(0)" ::: "memory");
    __builtin_amdgcn_s_barrier();
    __builtin_amdgcn_sched_barrier(0);
    if (kt < 31) PSTAGE(kt + 1, cb ^ 1);
    bf16x8 af[4], bfr[2];
#pragma unroll
    for (int i = 0; i < 4; ++i)
      af[i] = *(const bf16x8*)&As[cb][(wra * 64 + i * 16 + lq) * 32 + lg * 8];
#pragma unroll
    for (int j = 0; j < 2; ++j)
      bfr[j] = *(const bf16x8*)&Bs[cb][(wrb * 32 + j * 16 + lq) * 32 + lg * 8];
    __builtin_amdgcn_s_setprio(1);
#pragma unroll
    for (int i = 0; i < 4; ++i)
#pragma unroll
      for (int j = 0; j < 2; ++j)
        acc[i][j] = __builtin_amdgcn_mfma_f32_16x16x32_bf16(af[i], bfr[j], acc[i][j], 0, 0, 0);
    __builtin_amdgcn_s_setprio(0);
  }
#undef PSTAGE

  const int Ar = ra0 + wra * 64, Br = rb0 + wrb * 32;
#pragma unroll
  for (int i = 0; i < 4; ++i)
#pragma unroll
    for (int j = 0; j < 2; ++j) {
      const int e0 = Ar + i * 16 + lg * 4;
      const int m = Br + j * 16 + lq;
      *(f32x4*)&out[m * 1024 + e0] = acc[i][j];
    }
}

// ---------------- flash attention: 8 waves x 16 q-rows, KVBLK=128, batched-QK inner ------------
// Pass 1: all K ds_reads + QK MFMAs (fills MFMA queue); pass 2: per-kk softmax + PV.
__global__ __launch_bounds__(512, 4) void attn_kernel(const u16* __restrict__ Q,
                                                      const u16* __restrict__ K,
                                                      const u16* __restrict__ Vt,
                                                      u16* __restrict__ Z) {
  __shared__ __align__(16) u16 Ktile[2][8192];   // 128 keys x 64 d, chunk-swizzled (mod-8)
  __shared__ __align__(16) u16 Vtile[2][8192];   // 64 d x 128 keys, chunk-swizzled (mod-16)
  const int tid = threadIdx.x;
  const int wv = tid >> 6, ln = tid & 63;
  const int lq = ln & 15, lg = ln >> 4;
  const bool lgodd = (lg & 1) != 0;
  const int id = blockIdx.x;
  const int within = id >> 3;                      // 0..63
  const int xg = id & 7;                           // XCD group (L2 locality)
  int bh, qt;
  if (within < 32) { bh = xg * 4 + (within >> 4);     qt = 15 - (within & 15); }
  else { const int w = within - 32; bh = xg * 4 + 2 + (w >> 4); qt = w & 15; }
  const int qrow = (qt << 7) + wv * 16 + lq;       // this thread's q row
  const u16* Qp = Q + (size_t)bh * S_ * Dh_;
  const u16* Kp = K + (size_t)bh * S_ * Dh_;
  const u16* Vp = Vt + (size_t)bh * Dh_ * S_;

  // staging: 1024 16B-chunks per tile kind; 512 threads x 2 chunks each
  int kgofs[2], vgrow[2], vgcol[2];
#pragma unroll
  for (int j = 0; j < 2; ++j) {
    const int p = j * 512 + tid;                   // 0..1023 chunk id
    const int gk = p ^ ((p >> 3) & 7);             // K: row=p>>3 (0..127), col swizzled mod 8
    kgofs[j] = (gk >> 3) * 64 + (gk & 7) * 8;
    vgrow[j] = p >> 4;                             // V: row=d (0..63), col swizzled mod 16
    vgcol[j] = ((p & 15) ^ ((p >> 4) & 15)) * 8;
  }
  const int sc0 = (lg ^ (lq & 7)) * 8;             // K read cols (d-half 0)
  const int sc1 = ((4 + lg) ^ (lq & 7)) * 8;       // K read cols (d-half 1)

  bf16x8 qf0 = *(const bf16x8*)&Qp[qrow * Dh_ + lg * 8];
  bf16x8 qf1 = *(const bf16x8*)&Qp[qrow * Dh_ + 32 + lg * 8];

  f32x4 o[4];
  const f32x4 z4 = {0.f, 0.f, 0.f, 0.f};
#pragma unroll
  for (int dt = 0; dt < 4; ++dt) o[dt] = z4;
  float l_lane = 0.f;

#define STAGE(KT, BUF) do { const int kb_ = (KT) * 128;                              \
    gload16(Kp + (size_t)kb_ * 64 + kgofs[0], &Ktile[BUF][wv * 512]);                \
    gload16(Kp + (size_t)kb_ * 64 + kgofs[1], &Ktile[BUF][4096 + wv * 512]);         \
    gload16(Vp + (size_t)vgrow[0] * 2048 + kb_ + vgcol[0], &Vtile[BUF][wv * 512]);   \
    gload16(Vp + (size_t)vgrow[1] * 2048 + kb_ + vgcol[1], &Vtile[BUF][4096 + wv * 512]); \
  } while (0)

  STAGE(0, 0);

  int cur = 0;
  for (int kt = 0; kt <= qt; ++kt) {
    asm volatile("s_waitcnt vmcnt(0)" ::: "memory");   // own stage of tile kt drained
    __builtin_amdgcn_s_barrier();                      // all stages landed; old reads done
    __builtin_amdgcn_sched_barrier(0);
    if (kt < qt) STAGE(kt + 1, cur ^ 1);
    const int k0 = kt * 128;
    const bool diag = (kt == qt);
    const int nkk = diag ? ((wv >> 1) + 1) : 4;    // diag: skip fully-masked 32-key slices

    // ---- pass 1: batched QK^T for all live slices (fills MFMA pipe) ----
    f32x4 sa[4], sb[4];
    __builtin_amdgcn_s_setprio(1);
#pragma unroll
    for (int kk = 0; kk < 4; ++kk) {
      if (kk < nkk) {
        const int rA = (kk * 32 + lq) * 64;        // keys kk*32 + 0..15
        const int rB = rA + 1024;                  // +16 keys
        bf16x8 kA0 = *(const bf16x8*)&Ktile[cur][rA + sc0];
        bf16x8 kA1 = *(const bf16x8*)&Ktile[cur][rA + sc1];
        bf16x8 kB0 = *(const bf16x8*)&Ktile[cur][rB + sc0];
        bf16x8 kB1 = *(const bf16x8*)&Ktile[cur][rB + sc1];
        f32x4 a = z4, b = z4;
        a = __builtin_amdgcn_mfma_f32_16x16x32_bf16(kA0, qf0, a, 0, 0, 0);
        a = __builtin_amdgcn_mfma_f32_16x16x32_bf16(kA1, qf1, a, 0, 0, 0);
        b = __builtin_amdgcn_mfma_f32_16x16x32_bf16(kB0, qf0, b, 0, 0, 0);
        b = __builtin_amdgcn_mfma_f32_16x16x32_bf16(kB1, qf1, b, 0, 0, 0);
        sa[kk] = a; sb[kk] = b;
      }
    }
    __builtin_amdgcn_s_setprio(0);

    // ---- pass 2: per-slice softmax + route + PV (V reads issue under exp2 chains) ----
#pragma unroll
    for (int kk = 0; kk < 4; ++kk) {
      if (kk < nkk) {
        f32x4 xa = sa[kk], xb = sb[kk];
        if (diag) {
          const int keyA = k0 + kk * 32 + lg * 4;
          const int keyB = keyA + 16;
#pragma unroll
          for (int r = 0; r < 4; ++r) {
            if (keyA + r > qrow) xa[r] = -3.0e38f;
            if (keyB + r > qrow) xb[r] = -3.0e38f;
          }
        }
        // fixed-max softmax (log2 domain; scores bounded, exp2 can't overflow)
        float e0 = __builtin_amdgcn_exp2f(xa[0]);
        float e1 = __builtin_amdgcn_exp2f(xa[1]);
        float e2 = __builtin_amdgcn_exp2f(xa[2]);
        float e3 = __builtin_amdgcn_exp2f(xa[3]);
        float f0 = __builtin_amdgcn_exp2f(xb[0]);
        float f1 = __builtin_amdgcn_exp2f(xb[1]);
        float f2 = __builtin_amdgcn_exp2f(xb[2]);
        float f3 = __builtin_amdgcn_exp2f(xb[3]);
        l_lane += ((e0 + e1) + (e2 + e3)) + ((f0 + f1) + (f2 + f3));
        u32 A0, A1, B0, B1;
        asm("v_cvt_pk_bf16_f32 %0, %1, %2" : "=v"(A0) : "v"(e0), "v"(e1));
        asm("v_cvt_pk_bf16_f32 %0, %1, %2" : "=v"(A1) : "v"(e2), "v"(e3));
        asm("v_cvt_pk_bf16_f32 %0, %1, %2" : "=v"(B0) : "v"(f0), "v"(f1));
        asm("v_cvt_pk_bf16_f32 %0, %1, %2" : "=v"(B1) : "v"(f2), "v"(f3));
        // in-register P^T routing (verified R6-R15)
        asm("v_permlane32_swap_b32 %0, %1" : "+v"(A0), "+v"(B0));
        asm("v_permlane32_swap_b32 %0, %1" : "+v"(A1), "+v"(B1));
        const u32 A0x = __shfl_xor((int)A0, 16), B0x = __shfl_xor((int)B0, 16);
        const u32 A1x = __shfl_xor((int)A1, 16), B1x = __shfl_xor((int)B1, 16);
        u32x4 w;
        w[0] = lgodd ? B0x : A0;
        w[1] = lgodd ? B1x : A1;
        w[2] = lgodd ? B0 : A0x;
        w[3] = lgodd ? B1 : A1x;
        const bf16x8 pf = __builtin_bit_cast(bf16x8, w);
        const int scvk = ((kk * 4 + lg) ^ lq) * 8;
        __builtin_amdgcn_s_setprio(1);
#pragma unroll
        for (int dt = 0; dt < 4; ++dt) {
          bf16x8 vf = *(const bf16x8*)&Vtile[cur][(dt * 16 + lq) * 128 + scvk];
          o[dt] = __builtin_amdgcn_mfma_f32_16x16x32_bf16(vf, pf, o[dt], 0, 0, 0);
        }
        __builtin_amdgcn_s_setprio(0);
      }
    }
    cur ^= 1;
  }
#undef STAGE

  // epilogue: reduce row-sum across lg groups, apply 1/l and the quirk's extra /8
  float l = l_lane;
  l += __shfl_xor(l, 16);
  l += __shfl_xor(l, 32);
  const float inv = 0.125f / l;
#pragma unroll
  for (int dt = 0; dt < 4; ++dt) {
    u16x4 pko;
#pragma unroll
    for (int r = 0; r < 4; ++r) pko[r] = f2bf(o[dt][r] * inv);
    *(u16x4*)&Z[((size_t)bh * S_ + qrow) * Dh_ + dt * 16 + lg * 4] = pko;
  }
}

extern "C" void kernel_launch(void* const* d_in, const int* in_sizes, int n_in,
                              void* d_out, int out_size, void* d_ws, size_t ws_size,
                              hipStream_t stream) {
  const float* x    = (const float*)d_in[0];
  const float* Wq   = (const float*)d_in[1];
  const float* bq   = (const float*)d_in[2];
  const float* Wk   = (const float*)d_in[3];
  const float* bk   = (const float*)d_in[4];
  const float* Wv   = (const float*)d_in[5];
  const float* bv   = (const float*)d_in[6];
  const float* proj = (const float*)d_in[7];
  float* out = (float*)d_out;

  char* p = (char*)d_ws;
  u16* xb   = (u16*)p; p += (size_t)4096 * 1024 * 2;
  u16* wcat = (u16*)p; p += (size_t)3072 * 1024 * 2;
  u16* pjt  = (u16*)p; p += (size_t)1024 * 1024 * 2;
  u16* Qb   = (u16*)p; p += (size_t)4096 * 1024 * 2;
  u16* Kb   = (u16*)p; p += (size_t)4096 * 1024 * 2;
  u16* Vtb  = (u16*)p; p += (size_t)4096 * 1024 * 2;
  u16* Zb   = (u16*)p; p += (size_t)4096 * 1024 * 2;

  cvt_all<<<dim3(4608), dim3(256), 0, stream>>>(x, Wq, Wk, Wv, proj, xb, wcat, pjt);

  const float qs = 0.125f * 1.44269504f;  // fold score-scale + log2e into Q
  qkv_gemm<<<dim3(256), dim3(512), 0, stream>>>(wcat, xb, bq, bk, bv, Qb, Kb, Vtb, qs);

  attn_kernel<<<dim3(512), dim3(512), 0, stream>>>(Qb, Kb, Vtb, Zb);

  proj_gemm<<<dim3(512), dim3(256), 0, stream>>>(pjt, Zb, out);
}

// Round 17
// 97.698 us; speedup vs baseline: 1.1025x; 1.0100x over previous
//
#include <hip/hip_runtime.h>
#include <hip/hip_bf16.h>

typedef unsigned short u16;
typedef unsigned int u32;
typedef __bf16 bf16x8 __attribute__((ext_vector_type(8)));
typedef float f32x4 __attribute__((ext_vector_type(4)));
typedef u16 u16x8 __attribute__((ext_vector_type(8)));
typedef u16 u16x4 __attribute__((ext_vector_type(4)));
typedef u32 u32x4 __attribute__((ext_vector_type(4)));

#define B_ 2
#define S_ 2048
#define E_ 1024
#define H_ 16
#define Dh_ 64

static __device__ __forceinline__ u16 f2bf(float f) {
  unsigned u = __builtin_bit_cast(unsigned, f);
  u += 0x7fff + ((u >> 16) & 1);   // RNE
  return (u16)(u >> 16);
}

static __device__ __forceinline__ void gload16(const u16* g, u16* l) {
  __builtin_amdgcn_global_load_lds((const __attribute__((address_space(1))) unsigned int*)g,
                                   (__attribute__((address_space(3))) unsigned int*)l,
                                   16, 0, 0);
}

// ---------------- fused fp32 -> bf16 convert: x, Wq|Wk|Wv -> wcat; proj -> projT ----------------
__global__ void cvt_all(const float* __restrict__ x, const float* __restrict__ wq,
                        const float* __restrict__ wk, const float* __restrict__ wv,
                        const float* __restrict__ proj,
                        u16* __restrict__ xb, u16* __restrict__ wcat, u16* __restrict__ pjt) {
  __shared__ float tt[32][33];
  const int bid = blockIdx.x;
  const int tid = threadIdx.x;
  if (bid < 3584) {
    const int i = bid * 256 + tid;                   // 0..917503, exact
    const float* src; u16x8* dst;
    if (i < 524288) {
      src = x + (size_t)i * 8;            dst = (u16x8*)xb + i;
    } else {
      const int j = i - 524288;                      // 0..393215
      dst = (u16x8*)wcat + j;
      if (j < 131072)      src = wq + (size_t)j * 8;
      else if (j < 262144) src = wk + (size_t)(j - 131072) * 8;
      else                 src = wv + (size_t)(j - 262144) * 8;
    }
    float4 a = ((const float4*)src)[0], b = ((const float4*)src)[1];
    u16x8 o;
    o[0] = f2bf(a.x); o[1] = f2bf(a.y); o[2] = f2bf(a.z); o[3] = f2bf(a.w);
    o[4] = f2bf(b.x); o[5] = f2bf(b.y); o[6] = f2bf(b.z); o[7] = f2bf(b.w);
    *dst = o;
  } else {
    const int tb = bid - 3584;                       // 0..1023
    const int e0 = (tb & 31) * 32, f0 = (tb >> 5) * 32;
    const int tx = tid & 31, ty = tid >> 5;          // 32 x 8
#pragma unroll
    for (int r = 0; r < 4; ++r) {
      const int row = ty + r * 8;
      tt[row][tx] = proj[(f0 + row) * 1024 + e0 + tx];
    }
    __syncthreads();
#pragma unroll
    for (int r = 0; r < 4; ++r) {
      const int row = ty + r * 8;
      pjt[(e0 + row) * 1024 + f0 + tx] = f2bf(tt[tx][row]);
    }
  }
}

// ---------------- fused QKV GEMM: 192x256 tile, 8 waves, 4-phase/K-tile, grid 256 (R15) -------
__global__ __launch_bounds__(512, 2) void qkv_gemm(const u16* __restrict__ Wcat,
                                                   const u16* __restrict__ Xm,
                                                   const float* __restrict__ bq,
                                                   const float* __restrict__ bk,
                                                   const float* __restrict__ bv,
                                                   u16* __restrict__ Qb, u16* __restrict__ Kb,
                                                   u16* __restrict__ Vtb, float qs) {
  __shared__ __align__(16) u16 Alds[2][12288];   // 192 rows x 64 k
  __shared__ __align__(16) u16 Blds[2][16384];   // 256 rows x 64 k
  const int tid = threadIdx.x;                   // 0..511
  const int wv = tid >> 6, ln = tid & 63;
  const int lq = ln & 15, lg = ln >> 4;
  const int wm = wv >> 2, wn = wv & 3;           // wave grid 2(M) x 4(N)
  const int bid = blockIdx.x;
  const int xcd = bid & 7, w = bid >> 3;         // w 0..31
  const int bx = w & 15;                         // 0..15 (M tiles of 192)
  const int by = xcd * 2 + (w >> 4);             // 0..15 (N tiles of 256)
  const int ra0 = bx * 192, rb0 = by * 256;

  // staging: thread t stages LDS chunk G*512+t; source col pre-swizzled (c ^ row&7)
  const int r_t = tid >> 3, c_t = tid & 7;       // row-in-group 0..63, chunk 0..7
  const int gcol = (c_t ^ (r_t & 7)) * 8;        // swizzled source k-offset (u16)
  const u16* Asrc = Wcat + (ra0 + r_t) * 1024 + gcol;
  const u16* Bsrc = Xm   + (rb0 + r_t) * 1024 + gcol;

  // fragment read offsets (swizzled): chunk pos = (kh*4+lg) ^ (lq&7)
  const int sc0 = (lg ^ (lq & 7)) * 8;
  const int sc1 = ((4 + lg) ^ (lq & 7)) * 8;
  const int baseA = (wm * 96 + lq) * 64;         // + mh*3072 + ii*1024 + sc
  const int baseB = (wn * 64 + lq) * 64;         // + j*1024 + sc

  f32x4 acc[6][4];
  const f32x4 z4 = {0.f, 0.f, 0.f, 0.f};
#pragma unroll
  for (int i = 0; i < 6; ++i)
#pragma unroll
    for (int j = 0; j < 4; ++j) acc[i][j] = z4;

#define SA(G, KT, BUF) gload16(Asrc + (G) * 65536 + (KT) * 64, &Alds[BUF][((G) * 512 + tid) * 8])
#define SB(G, KT, BUF) gload16(Bsrc + (G) * 65536 + (KT) * 64, &Blds[BUF][((G) * 512 + tid) * 8])
#define LOADA(MH, SC) do {                                                         \
    _Pragma("unroll") for (int ii = 0; ii < 3; ++ii)                               \
      af[ii] = *(const bf16x8*)&Alds[cb][baseA + (MH) * 3072 + ii * 1024 + (SC)];  \
  } while (0)
#define LOADB(DST, SC) do {                                                        \
    _Pragma("unroll") for (int j = 0; j < 4; ++j)                                  \
      DST[j] = *(const bf16x8*)&Blds[cb][baseB + j * 1024 + (SC)];                 \
  } while (0)
#define MF(MH, BQ) do {                                                            \
    _Pragma("unroll") for (int ii = 0; ii < 3; ++ii)                               \
      _Pragma("unroll") for (int j = 0; j < 4; ++j)                                \
        acc[(MH) * 3 + ii][j] =                                                    \
            __builtin_amdgcn_mfma_f32_16x16x32_bf16(af[ii], BQ[j],                 \
                                                    acc[(MH) * 3 + ii][j], 0, 0, 0); \
  } while (0)

  // prologue: stage tile 0 (7 loads/thread)
  SB(0, 0, 0); SB(1, 0, 0); SB(2, 0, 0); SB(3, 0, 0);
  SA(0, 0, 0); SA(1, 0, 0); SA(2, 0, 0);

  for (int kt = 0; kt < 16; ++kt) {
    const int cb = kt & 1, nb = cb ^ 1;
    const bool st = (kt < 15);
    asm volatile("s_waitcnt vmcnt(0)" ::: "memory");   // all stages of tile kt landed
    __builtin_amdgcn_s_barrier();
    __builtin_amdgcn_sched_barrier(0);
    bf16x8 af[3], bq0[4], bq1[4];
    // phase 0: (mh0, kh0)
    LOADA(0, sc0);
    LOADB(bq0, sc0);
    if (st) { SB(0, kt + 1, nb); SB(1, kt + 1, nb); }
    __builtin_amdgcn_s_barrier();
    asm volatile("s_waitcnt lgkmcnt(0)" ::: "memory");
    __builtin_amdgcn_sched_barrier(0);
    __builtin_amdgcn_s_setprio(1);
    MF(0, bq0);
    __builtin_amdgcn_s_setprio(0);
    __builtin_amdgcn_s_barrier();
    // phase 1: (mh0, kh1)
    LOADA(0, sc1);
    LOADB(bq1, sc1);
    if (st) { SB(2, kt + 1, nb); SB(3, kt + 1, nb); }
    __builtin_amdgcn_s_barrier();
    asm volatile("s_waitcnt lgkmcnt(0)" ::: "memory");
    __builtin_amdgcn_sched_barrier(0);
    __builtin_amdgcn_s_setprio(1);
    MF(0, bq1);
    __builtin_amdgcn_s_setprio(0);
    __builtin_amdgcn_s_barrier();
    // phase 2: (mh1, kh0)
    LOADA(1, sc0);
    if (st) { SA(0, kt + 1, nb); SA(1, kt + 1, nb); }
    __builtin_amdgcn_s_barrier();
    asm volatile("s_waitcnt lgkmcnt(0)" ::: "memory");
    __builtin_amdgcn_sched_barrier(0);
    __builtin_amdgcn_s_setprio(1);
    MF(1, bq0);
    __builtin_amdgcn_s_setprio(0);
    __builtin_amdgcn_s_barrier();
    // phase 3: (mh1, kh1)
    LOADA(1, sc1);
    if (st) { SA(2, kt + 1, nb); }
    __builtin_amdgcn_s_barrier();
    asm volatile("s_waitcnt lgkmcnt(0)" ::: "memory");
    __builtin_amdgcn_sched_barrier(0);
    __builtin_amdgcn_s_setprio(1);
    MF(1, bq1);
    __builtin_amdgcn_s_setprio(0);
    __builtin_amdgcn_s_barrier();
  }
#undef SA
#undef SB
#undef LOADA
#undef LOADB
#undef MF

  // epilogue: region per fragment (16-row frags never straddle a 1024 boundary)
#pragma unroll
  for (int i = 0; i < 6; ++i) {
    const int n0 = ra0 + wm * 96 + i * 16 + lg * 4;
    const int reg_i = n0 >> 10;                  // 0=Q 1=K 2=V, wave-uniform per frag
    const int nl = n0 & 1023;
    const int h = nl >> 6, d = nl & 63;
    const float* bias = (reg_i == 0) ? bq : (reg_i == 1) ? bk : bv;
    const float osc = (reg_i == 0) ? qs : 1.0f;
    const float4 b4 = *(const float4*)&bias[nl];
#pragma unroll
    for (int j = 0; j < 4; ++j) {
      const int m = rb0 + wn * 64 + j * 16 + lq;
      const int bb = m >> 11, s = m & 2047;
      if (reg_i < 2) {
        u16* out = (reg_i == 0) ? Qb : Kb;
        u16x4 pk;
        pk[0] = f2bf((acc[i][j][0] + b4.x) * osc);
        pk[1] = f2bf((acc[i][j][1] + b4.y) * osc);
        pk[2] = f2bf((acc[i][j][2] + b4.z) * osc);
        pk[3] = f2bf((acc[i][j][3] + b4.w) * osc);
        *(u16x4*)&out[((bb * H_ + h) * S_ + s) * Dh_ + d] = pk;
      } else {
        const float bvv[4] = {b4.x, b4.y, b4.z, b4.w};
#pragma unroll
        for (int r = 0; r < 4; ++r)
          Vtb[((bb * H_ + h) * Dh_ + d + r) * S_ + s] = f2bf(acc[i][j][r] + bvv[r]);
      }
    }
  }
}

// ---------------- proj GEMM: 128(e)x128(m) tile, 8 waves, 2-phase/K-tile, grid 256 (qkv clone) --
// out[m][e] = sum_k pjt[e][k] * Z[m][k]. 8x32 tiles -> 256 blocks, 1/CU. LDS 64 KB.
__global__ __launch_bounds__(512, 2) void proj_gemm(const u16* __restrict__ Am,
                                                    const u16* __restrict__ Bm,
                                                    float* __restrict__ out) {
  __shared__ __align__(16) u16 Alds[2][8192];    // 128 rows x 64 k
  __shared__ __align__(16) u16 Blds[2][8192];
  const int tid = threadIdx.x;                   // 0..511
  const int wv = tid >> 6, ln = tid & 63;
  const int lq = ln & 15, lg = ln >> 4;
  const int wm = wv >> 2, wn = wv & 3;           // wave grid 2(M=e) x 4(N=m)
  const int bid = blockIdx.x;
  const int xcd = bid & 7, w = bid >> 3;         // w 0..31
  const int bx = w & 7;                          // 0..7  (e tiles of 128)
  const int by = xcd * 4 + (w >> 3);             // 0..31 (m tiles of 128)
  const int ra0 = bx * 128, rb0 = by * 128;

  const int r_t = tid >> 3, c_t = tid & 7;       // row-in-group 0..63, chunk 0..7
  const int gcol = (c_t ^ (r_t & 7)) * 8;        // swizzled source k-offset (u16)
  const u16* Asrc = Am + (ra0 + r_t) * 1024 + gcol;
  const u16* Bsrc = Bm + (rb0 + r_t) * 1024 + gcol;

  const int sc0 = (lg ^ (lq & 7)) * 8;
  const int sc1 = ((4 + lg) ^ (lq & 7)) * 8;
  const int baseA = (wm * 64 + lq) * 64;         // + ii*1024 + sc
  const int baseB = (wn * 32 + lq) * 64;         // + j*1024 + sc

  f32x4 acc[4][2];
  const f32x4 z4 = {0.f, 0.f, 0.f, 0.f};
#pragma unroll
  for (int i = 0; i < 4; ++i)
#pragma unroll
    for (int j = 0; j < 2; ++j) acc[i][j] = z4;

#define SA(G, KT, BUF) gload16(Asrc + (G) * 65536 + (KT) * 64, &Alds[BUF][((G) * 512 + tid) * 8])
#define SB(G, KT, BUF) gload16(Bsrc + (G) * 65536 + (KT) * 64, &Blds[BUF][((G) * 512 + tid) * 8])
#define LOADAB(SC) do {                                                            \
    _Pragma("unroll") for (int ii = 0; ii < 4; ++ii)                               \
      af[ii] = *(const bf16x8*)&Alds[cb][baseA + ii * 1024 + (SC)];                \
    _Pragma("unroll") for (int j = 0; j < 2; ++j)                                  \
      bf[j] = *(const bf16x8*)&Blds[cb][baseB + j * 1024 + (SC)];                  \
  } while (0)
#define MF() do {                                                                  \
    _Pragma("unroll") for (int ii = 0; ii < 4; ++ii)                               \
      _Pragma("unroll") for (int j = 0; j < 2; ++j)                                \
        acc[ii][j] = __builtin_amdgcn_mfma_f32_16x16x32_bf16(af[ii], bf[j],        \
                                                             acc[ii][j], 0, 0, 0); \
  } while (0)

  // prologue: stage tile 0 (4 loads/thread)
  SA(0, 0, 0); SA(1, 0, 0); SB(0, 0, 0); SB(1, 0, 0);

  for (int kt = 0; kt < 16; ++kt) {
    const int cb = kt & 1, nb = cb ^ 1;
    const bool st = (kt < 15);
    asm volatile("s_waitcnt vmcnt(0)" ::: "memory");   // all stages of tile kt landed
    __builtin_amdgcn_s_barrier();
    __builtin_amdgcn_sched_barrier(0);
    bf16x8 af[4], bf[2];
    // phase 0: kh0
    LOADAB(sc0);
    if (st) { SA(0, kt + 1, nb); SA(1, kt + 1, nb); }
    __builtin_amdgcn_s_barrier();
    asm volatile("s_waitcnt lgkmcnt(0)" ::: "memory");
    __builtin_amdgcn_sched_barrier(0);
    __builtin_amdgcn_s_setprio(1);
    MF();
    __builtin_amdgcn_s_setprio(0);
    __builtin_amdgcn_s_barrier();
    // phase 1: kh1
    LOADAB(sc1);
    if (st) { SB(0, kt + 1, nb); SB(1, kt + 1, nb); }
    __builtin_amdgcn_s_barrier();
    asm volatile("s_waitcnt lgkmcnt(0)" ::: "memory");
    __builtin_amdgcn_sched_barrier(0);
    __builtin_amdgcn_s_setprio(1);
    MF();
    __builtin_amdgcn_s_setprio(0);
    __builtin_amdgcn_s_barrier();
  }
#undef SA
#undef SB
#undef LOADAB
#undef MF

#pragma unroll
  for (int i = 0; i < 4; ++i)
#pragma unroll
    for (int j = 0; j < 2; ++j) {
      const int e0 = ra0 + wm * 64 + i * 16 + lg * 4;
      const int m = rb0 + wn * 32 + j * 16 + lq;
      *(f32x4*)&out[m * 1024 + e0] = acc[i][j];
    }
}

// ---------------- flash attention: 8 waves x 16 q-rows, KVBLK=128, batched-QK inner (R16) -------
__global__ __launch_bounds__(512, 4) void attn_kernel(const u16* __restrict__ Q,
                                                      const u16* __restrict__ K,
                                                      const u16* __restrict__ Vt,
                                                      u16* __restrict__ Z) {
  __shared__ __align__(16) u16 Ktile[2][8192];   // 128 keys x 64 d, chunk-swizzled (mod-8)
  __shared__ __align__(16) u16 Vtile[2][8192];   // 64 d x 128 keys, chunk-swizzled (mod-16)
  const int tid = threadIdx.x;
  const int wv = tid >> 6, ln = tid & 63;
  const int lq = ln & 15, lg = ln >> 4;
  const bool lgodd = (lg & 1) != 0;
  const int id = blockIdx.x;
  const int within = id >> 3;                      // 0..63
  const int xg = id & 7;                           // XCD group (L2 locality)
  int bh, qt;
  if (within < 32) { bh = xg * 4 + (within >> 4);     qt = 15 - (within & 15); }
  else { const int w = within - 32; bh = xg * 4 + 2 + (w >> 4); qt = w & 15; }
  const int qrow = (qt << 7) + wv * 16 + lq;       // this thread's q row
  const u16* Qp = Q + (size_t)bh * S_ * Dh_;
  const u16* Kp = K + (size_t)bh * S_ * Dh_;
  const u16* Vp = Vt + (size_t)bh * Dh_ * S_;

  // staging: 1024 16B-chunks per tile kind; 512 threads x 2 chunks each
  int kgofs[2], vgrow[2], vgcol[2];
#pragma unroll
  for (int j = 0; j < 2; ++j) {
    const int p = j * 512 + tid;                   // 0..1023 chunk id
    const int gk = p ^ ((p >> 3) & 7);             // K: row=p>>3 (0..127), col swizzled mod 8
    kgofs[j] = (gk >> 3) * 64 + (gk & 7) * 8;
    vgrow[j] = p >> 4;                             // V: row=d (0..63), col swizzled mod 16
    vgcol[j] = ((p & 15) ^ ((p >> 4) & 15)) * 8;
  }
  const int sc0 = (lg ^ (lq & 7)) * 8;             // K read cols (d-half 0)
  const int sc1 = ((4 + lg) ^ (lq & 7)) * 8;       // K read cols (d-half 1)

  bf16x8 qf0 = *(const bf16x8*)&Qp[qrow * Dh_ + lg * 8];
  bf16x8 qf1 = *(const bf16x8*)&Qp[qrow * Dh_ + 32 + lg * 8];

  f32x4 o[4];
  const f32x4 z4 = {0.f, 0.f, 0.f, 0.f};
#pragma unroll
  for (int dt = 0; dt < 4; ++dt) o[dt] = z4;
  float l_lane = 0.f;

#define STAGE(KT, BUF) do { const int kb_ = (KT) * 128;                              \
    gload16(Kp + (size_t)kb_ * 64 + kgofs[0], &Ktile[BUF][wv * 512]);                \
    gload16(Kp + (size_t)kb_ * 64 + kgofs[1], &Ktile[BUF][4096 + wv * 512]);         \
    gload16(Vp + (size_t)vgrow[0] * 2048 + kb_ + vgcol[0], &Vtile[BUF][wv * 512]);   \
    gload16(Vp + (size_t)vgrow[1] * 2048 + kb_ + vgcol[1], &Vtile[BUF][4096 + wv * 512]); \
  } while (0)

  STAGE(0, 0);

  int cur = 0;
  for (int kt = 0; kt <= qt; ++kt) {
    asm volatile("s_waitcnt vmcnt(0)" ::: "memory");   // own stage of tile kt drained
    __builtin_amdgcn_s_barrier();                      // all stages landed; old reads done
    __builtin_amdgcn_sched_barrier(0);
    if (kt < qt) STAGE(kt + 1, cur ^ 1);
    const int k0 = kt * 128;
    const bool diag = (kt == qt);
    const int nkk = diag ? ((wv >> 1) + 1) : 4;    // diag: skip fully-masked 32-key slices

    // ---- pass 1: batched QK^T for all live slices (fills MFMA pipe) ----
    f32x4 sa[4], sb[4];
    __builtin_amdgcn_s_setprio(1);
#pragma unroll
    for (int kk = 0; kk < 4; ++kk) {
      if (kk < nkk) {
        const int rA = (kk * 32 + lq) * 64;        // keys kk*32 + 0..15
        const int rB = rA + 1024;                  // +16 keys
        bf16x8 kA0 = *(const bf16x8*)&Ktile[cur][rA + sc0];
        bf16x8 kA1 = *(const bf16x8*)&Ktile[cur][rA + sc1];
        bf16x8 kB0 = *(const bf16x8*)&Ktile[cur][rB + sc0];
        bf16x8 kB1 = *(const bf16x8*)&Ktile[cur][rB + sc1];
        f32x4 a = z4, b = z4;
        a = __builtin_amdgcn_mfma_f32_16x16x32_bf16(kA0, qf0, a, 0, 0, 0);
        a = __builtin_amdgcn_mfma_f32_16x16x32_bf16(kA1, qf1, a, 0, 0, 0);
        b = __builtin_amdgcn_mfma_f32_16x16x32_bf16(kB0, qf0, b, 0, 0, 0);
        b = __builtin_amdgcn_mfma_f32_16x16x32_bf16(kB1, qf1, b, 0, 0, 0);
        sa[kk] = a; sb[kk] = b;
      }
    }
    __builtin_amdgcn_s_setprio(0);

    // ---- pass 2: per-slice softmax + route + PV (V reads issue under exp2 chains) ----
#pragma unroll
    for (int kk = 0; kk < 4; ++kk) {
      if (kk < nkk) {
        f32x4 xa = sa[kk], xb = sb[kk];
        if (diag) {
          const int keyA = k0 + kk * 32 + lg * 4;
          const int keyB = keyA + 16;
#pragma unroll
          for (int r = 0; r < 4; ++r) {
            if (keyA + r > qrow) xa[r] = -3.0e38f;
            if (keyB + r > qrow) xb[r] = -3.0e38f;
          }
        }
        // fixed-max softmax (log2 domain; scores bounded, exp2 can't overflow)
        float e0 = __builtin_amdgcn_exp2f(xa[0]);
        float e1 = __builtin_amdgcn_exp2f(xa[1]);
        float e2 = __builtin_amdgcn_exp2f(xa[2]);
        float e3 = __builtin_amdgcn_exp2f(xa[3]);
        float f0 = __builtin_amdgcn_exp2f(xb[0]);
        float f1 = __builtin_amdgcn_exp2f(xb[1]);
        float f2 = __builtin_amdgcn_exp2f(xb[2]);
        float f3 = __builtin_amdgcn_exp2f(xb[3]);
        l_lane += ((e0 + e1) + (e2 + e3)) + ((f0 + f1) + (f2 + f3));
        u32 A0, A1, B0, B1;
        asm("v_cvt_pk_bf16_f32 %0, %1, %2" : "=v"(A0) : "v"(e0), "v"(e1));
        asm("v_cvt_pk_bf16_f32 %0, %1, %2" : "=v"(A1) : "v"(e2), "v"(e3));
        asm("v_cvt_pk_bf16_f32 %0, %1, %2" : "=v"(B0) : "v"(f0), "v"(f1));
        asm("v_cvt_pk_bf16_f32 %0, %1, %2" : "=v"(B1) : "v"(f2), "v"(f3));
        // in-register P^T routing (verified R6-R16)
        asm("v_permlane32_swap_b32 %0, %1" : "+v"(A0), "+v"(B0));
        asm("v_permlane32_swap_b32 %0, %1" : "+v"(A1), "+v"(B1));
        const u32 A0x = __shfl_xor((int)A0, 16), B0x = __shfl_xor((int)B0, 16);
        const u32 A1x = __shfl_xor((int)A1, 16), B1x = __shfl_xor((int)B1, 16);
        u32x4 w;
        w[0] = lgodd ? B0x : A0;
        w[1] = lgodd ? B1x : A1;
        w[2] = lgodd ? B0 : A0x;
        w[3] = lgodd ? B1 : A1x;
        const bf16x8 pf = __builtin_bit_cast(bf16x8, w);
        const int scvk = ((kk * 4 + lg) ^ lq) * 8;
        __builtin_amdgcn_s_setprio(1);
#pragma unroll
        for (int dt = 0; dt < 4; ++dt) {
          bf16x8 vf = *(const bf16x8*)&Vtile[cur][(dt * 16 + lq) * 128 + scvk];
          o[dt] = __builtin_amdgcn_mfma_f32_16x16x32_bf16(vf, pf, o[dt], 0, 0, 0);
        }
        __builtin_amdgcn_s_setprio(0);
      }
    }
    cur ^= 1;
  }
#undef STAGE

  // epilogue: reduce row-sum across lg groups, apply 1/l and the quirk's extra /8
  float l = l_lane;
  l += __shfl_xor(l, 16);
  l += __shfl_xor(l, 32);
  const float inv = 0.125f / l;
#pragma unroll
  for (int dt = 0; dt < 4; ++dt) {
    u16x4 pko;
#pragma unroll
    for (int r = 0; r < 4; ++r) pko[r] = f2bf(o[dt][r] * inv);
    *(u16x4*)&Z[((size_t)bh * S_ + qrow) * Dh_ + dt * 16 + lg * 4] = pko;
  }
}

extern "C" void kernel_launch(void* const* d_in, const int* in_sizes, int n_in,
                              void* d_out, int out_size, void* d_ws, size_t ws_size,
                              hipStream_t stream) {
  const float* x    = (const float*)d_in[0];
  const float* Wq   = (const float*)d_in[1];
  const float* bq   = (const float*)d_in[2];
  const float* Wk   = (const float*)d_in[3];
  const float* bk   = (const float*)d_in[4];
  const float* Wv   = (const float*)d_in[5];
  const float* bv   = (const float*)d_in[6];
  const float* proj = (const float*)d_in[7];
  float* out = (float*)d_out;

  char* p = (char*)d_ws;
  u16* xb   = (u16*)p; p += (size_t)4096 * 1024 * 2;
  u16* wcat = (u16*)p; p += (size_t)3072 * 1024 * 2;
  u16* pjt  = (u16*)p; p += (size_t)1024 * 1024 * 2;
  u16* Qb   = (u16*)p; p += (size_t)4096 * 1024 * 2;
  u16* Kb   = (u16*)p; p += (size_t)4096 * 1024 * 2;
  u16* Vtb  = (u16*)p; p += (size_t)4096 * 1024 * 2;
  u16* Zb   = (u16*)p; p += (size_t)4096 * 1024 * 2;

  cvt_all<<<dim3(4608), dim3(256), 0, stream>>>(x, Wq, Wk, Wv, proj, xb, wcat, pjt);

  const float qs = 0.125f * 1.44269504f;  // fold score-scale + log2e into Q
  qkv_gemm<<<dim3(256), dim3(512), 0, stream>>>(wcat, xb, bq, bk, bv, Qb, Kb, Vtb, qs);

  attn_kernel<<<dim3(512), dim3(512), 0, stream>>>(Qb, Kb, Vtb, Zb);

  proj_gemm<<<dim3(256), dim3(512), 0, stream>>>(pjt, Zb, out);
}

// Round 18
// 95.725 us; speedup vs baseline: 1.1252x; 1.0206x over previous
//
#include <hip/hip_runtime.h>
#include <hip/hip_bf16.h>

typedef unsigned short u16;
typedef unsigned int u32;
typedef __bf16 bf16x8 __attribute__((ext_vector_type(8)));
typedef float f32x4 __attribute__((ext_vector_type(4)));
typedef u16 u16x8 __attribute__((ext_vector_type(8)));
typedef u16 u16x4 __attribute__((ext_vector_type(4)));
typedef u32 u32x4 __attribute__((ext_vector_type(4)));

#define B_ 2
#define S_ 2048
#define E_ 1024
#define H_ 16
#define Dh_ 64

static __device__ __forceinline__ u16 f2bf(float f) {
  unsigned u = __builtin_bit_cast(unsigned, f);
  u += 0x7fff + ((u >> 16) & 1);   // RNE
  return (u16)(u >> 16);
}

static __device__ __forceinline__ void gload16(const u16* g, u16* l) {
  __builtin_amdgcn_global_load_lds((const __attribute__((address_space(1))) unsigned int*)g,
                                   (__attribute__((address_space(3))) unsigned int*)l,
                                   16, 0, 0);
}

// ---------------- fused fp32 -> bf16 convert: x, Wq|Wk|Wv -> wcat; proj -> projT ----------------
__global__ void cvt_all(const float* __restrict__ x, const float* __restrict__ wq,
                        const float* __restrict__ wk, const float* __restrict__ wv,
                        const float* __restrict__ proj,
                        u16* __restrict__ xb, u16* __restrict__ wcat, u16* __restrict__ pjt) {
  __shared__ float tt[32][33];
  const int bid = blockIdx.x;
  const int tid = threadIdx.x;
  if (bid < 3584) {
    const int i = bid * 256 + tid;                   // 0..917503, exact
    const float* src; u16x8* dst;
    if (i < 524288) {
      src = x + (size_t)i * 8;            dst = (u16x8*)xb + i;
    } else {
      const int j = i - 524288;                      // 0..393215
      dst = (u16x8*)wcat + j;
      if (j < 131072)      src = wq + (size_t)j * 8;
      else if (j < 262144) src = wk + (size_t)(j - 131072) * 8;
      else                 src = wv + (size_t)(j - 262144) * 8;
    }
    float4 a = ((const float4*)src)[0], b = ((const float4*)src)[1];
    u16x8 o;
    o[0] = f2bf(a.x); o[1] = f2bf(a.y); o[2] = f2bf(a.z); o[3] = f2bf(a.w);
    o[4] = f2bf(b.x); o[5] = f2bf(b.y); o[6] = f2bf(b.z); o[7] = f2bf(b.w);
    *dst = o;
  } else {
    const int tb = bid - 3584;                       // 0..1023
    const int e0 = (tb & 31) * 32, f0 = (tb >> 5) * 32;
    const int tx = tid & 31, ty = tid >> 5;          // 32 x 8
#pragma unroll
    for (int r = 0; r < 4; ++r) {
      const int row = ty + r * 8;
      tt[row][tx] = proj[(f0 + row) * 1024 + e0 + tx];
    }
    __syncthreads();
#pragma unroll
    for (int r = 0; r < 4; ++r) {
      const int row = ty + r * 8;
      pjt[(e0 + row) * 1024 + f0 + tx] = f2bf(tt[tx][row]);
    }
  }
}

// ---------------- fused QKV GEMM: 192x128 tile, 8 waves, 2-phase/K-tile, grid 512 (2/CU) -------
// Wcat bf16 [3072][1024] (M), Xm bf16 [4096][1024] (N). 16 x 32 tiles -> 512 blocks, 2/CU.
// LDS: A 192x64 (2 buf) + B 128x64 (2 buf) = 80 KB -> 2 blocks/CU = 4 waves/SIMD.
// Per-wave output 96x32: acc[6][2]; 2 phases (kh0, kh1), 12 MFMA each. Row-XOR chunk swizzle.
__global__ __launch_bounds__(512, 4) void qkv_gemm(const u16* __restrict__ Wcat,
                                                   const u16* __restrict__ Xm,
                                                   const float* __restrict__ bq,
                                                   const float* __restrict__ bk,
                                                   const float* __restrict__ bv,
                                                   u16* __restrict__ Qb, u16* __restrict__ Kb,
                                                   u16* __restrict__ Vtb, float qs) {
  __shared__ __align__(16) u16 Alds[2][12288];   // 192 rows x 64 k
  __shared__ __align__(16) u16 Blds[2][8192];    // 128 rows x 64 k
  const int tid = threadIdx.x;                   // 0..511
  const int wv = tid >> 6, ln = tid & 63;
  const int lq = ln & 15, lg = ln >> 4;
  const int wm = wv >> 2, wn = wv & 3;           // wave grid 2(M) x 4(N)
  const int bid = blockIdx.x;
  const int xcd = bid & 7, w = bid >> 3;         // w 0..63
  const int bx = w & 15;                         // 0..15 (M tiles of 192)
  const int by = xcd * 4 + (w >> 4);             // 0..31 (N tiles of 128)
  const int ra0 = bx * 192, rb0 = by * 128;

  // staging: thread t stages LDS chunk G*512+t; source col pre-swizzled (c ^ row&7)
  const int r_t = tid >> 3, c_t = tid & 7;       // row-in-group 0..63, chunk 0..7
  const int gcol = (c_t ^ (r_t & 7)) * 8;        // swizzled source k-offset (u16)
  const u16* Asrc = Wcat + (ra0 + r_t) * 1024 + gcol;
  const u16* Bsrc = Xm   + (rb0 + r_t) * 1024 + gcol;

  // fragment read offsets (swizzled): chunk pos = (kh*4+lg) ^ (lq&7)
  const int sc0 = (lg ^ (lq & 7)) * 8;
  const int sc1 = ((4 + lg) ^ (lq & 7)) * 8;
  const int baseA = (wm * 96 + lq) * 64;         // + ii*1024 + sc
  const int baseB = (wn * 32 + lq) * 64;         // + j*1024 + sc

  f32x4 acc[6][2];
  const f32x4 z4 = {0.f, 0.f, 0.f, 0.f};
#pragma unroll
  for (int i = 0; i < 6; ++i)
#pragma unroll
    for (int j = 0; j < 2; ++j) acc[i][j] = z4;

#define SA(G, KT, BUF) gload16(Asrc + (G) * 65536 + (KT) * 64, &Alds[BUF][((G) * 512 + tid) * 8])
#define SB(G, KT, BUF) gload16(Bsrc + (G) * 65536 + (KT) * 64, &Blds[BUF][((G) * 512 + tid) * 8])
#define LOADAB(SC) do {                                                            \
    _Pragma("unroll") for (int ii = 0; ii < 6; ++ii)                               \
      af[ii] = *(const bf16x8*)&Alds[cb][baseA + ii * 1024 + (SC)];                \
    _Pragma("unroll") for (int j = 0; j < 2; ++j)                                  \
      bfr[j] = *(const bf16x8*)&Blds[cb][baseB + j * 1024 + (SC)];                 \
  } while (0)
#define MF() do {                                                                  \
    _Pragma("unroll") for (int ii = 0; ii < 6; ++ii)                               \
      _Pragma("unroll") for (int j = 0; j < 2; ++j)                                \
        acc[ii][j] = __builtin_amdgcn_mfma_f32_16x16x32_bf16(af[ii], bfr[j],       \
                                                             acc[ii][j], 0, 0, 0); \
  } while (0)

  // prologue: stage tile 0 (5 loads/thread: A groups 0..2, B groups 0..1)
  SA(0, 0, 0); SA(1, 0, 0); SA(2, 0, 0); SB(0, 0, 0); SB(1, 0, 0);

  for (int kt = 0; kt < 16; ++kt) {
    const int cb = kt & 1, nb = cb ^ 1;
    const bool st = (kt < 15);
    asm volatile("s_waitcnt vmcnt(0)" ::: "memory");   // all stages of tile kt landed
    __builtin_amdgcn_s_barrier();
    __builtin_amdgcn_sched_barrier(0);
    bf16x8 af[6], bfr[2];
    // phase 0: kh0
    LOADAB(sc0);
    if (st) { SA(0, kt + 1, nb); SA(1, kt + 1, nb); SA(2, kt + 1, nb); }
    __builtin_amdgcn_s_barrier();
    asm volatile("s_waitcnt lgkmcnt(0)" ::: "memory");
    __builtin_amdgcn_sched_barrier(0);
    __builtin_amdgcn_s_setprio(1);
    MF();
    __builtin_amdgcn_s_setprio(0);
    __builtin_amdgcn_s_barrier();
    // phase 1: kh1
    LOADAB(sc1);
    if (st) { SB(0, kt + 1, nb); SB(1, kt + 1, nb); }
    __builtin_amdgcn_s_barrier();
    asm volatile("s_waitcnt lgkmcnt(0)" ::: "memory");
    __builtin_amdgcn_sched_barrier(0);
    __builtin_amdgcn_s_setprio(1);
    MF();
    __builtin_amdgcn_s_setprio(0);
    __builtin_amdgcn_s_barrier();
  }
#undef SA
#undef SB
#undef LOADAB
#undef MF

  // epilogue: region per fragment (16-row frags never straddle a 1024 boundary)
#pragma unroll
  for (int i = 0; i < 6; ++i) {
    const int n0 = ra0 + wm * 96 + i * 16 + lg * 4;
    const int reg_i = n0 >> 10;                  // 0=Q 1=K 2=V, wave-uniform per frag
    const int nl = n0 & 1023;
    const int h = nl >> 6, d = nl & 63;
    const float* bias = (reg_i == 0) ? bq : (reg_i == 1) ? bk : bv;
    const float osc = (reg_i == 0) ? qs : 1.0f;
    const float4 b4 = *(const float4*)&bias[nl];
#pragma unroll
    for (int j = 0; j < 2; ++j) {
      const int m = rb0 + wn * 32 + j * 16 + lq;
      const int bb = m >> 11, s = m & 2047;
      if (reg_i < 2) {
        u16* out = (reg_i == 0) ? Qb : Kb;
        u16x4 pk;
        pk[0] = f2bf((acc[i][j][0] + b4.x) * osc);
        pk[1] = f2bf((acc[i][j][1] + b4.y) * osc);
        pk[2] = f2bf((acc[i][j][2] + b4.z) * osc);
        pk[3] = f2bf((acc[i][j][3] + b4.w) * osc);
        *(u16x4*)&out[((bb * H_ + h) * S_ + s) * Dh_ + d] = pk;
      } else {
        const float bvv[4] = {b4.x, b4.y, b4.z, b4.w};
#pragma unroll
        for (int r = 0; r < 4; ++r)
          Vtb[((bb * H_ + h) * Dh_ + d + r) * S_ + s] = f2bf(acc[i][j][r] + bvv[r]);
      }
    }
  }
}

// ---------------- proj GEMM: 128(e)x128(m) tile, 8 waves, 2-phase/K-tile, grid 256 (R17) --------
__global__ __launch_bounds__(512, 2) void proj_gemm(const u16* __restrict__ Am,
                                                    const u16* __restrict__ Bm,
                                                    float* __restrict__ out) {
  __shared__ __align__(16) u16 Alds[2][8192];    // 128 rows x 64 k
  __shared__ __align__(16) u16 Blds[2][8192];
  const int tid = threadIdx.x;                   // 0..511
  const int wv = tid >> 6, ln = tid & 63;
  const int lq = ln & 15, lg = ln >> 4;
  const int wm = wv >> 2, wn = wv & 3;           // wave grid 2(M=e) x 4(N=m)
  const int bid = blockIdx.x;
  const int xcd = bid & 7, w = bid >> 3;         // w 0..31
  const int bx = w & 7;                          // 0..7  (e tiles of 128)
  const int by = xcd * 4 + (w >> 3);             // 0..31 (m tiles of 128)
  const int ra0 = bx * 128, rb0 = by * 128;

  const int r_t = tid >> 3, c_t = tid & 7;       // row-in-group 0..63, chunk 0..7
  const int gcol = (c_t ^ (r_t & 7)) * 8;        // swizzled source k-offset (u16)
  const u16* Asrc = Am + (ra0 + r_t) * 1024 + gcol;
  const u16* Bsrc = Bm + (rb0 + r_t) * 1024 + gcol;

  const int sc0 = (lg ^ (lq & 7)) * 8;
  const int sc1 = ((4 + lg) ^ (lq & 7)) * 8;
  const int baseA = (wm * 64 + lq) * 64;         // + ii*1024 + sc
  const int baseB = (wn * 32 + lq) * 64;         // + j*1024 + sc

  f32x4 acc[4][2];
  const f32x4 z4 = {0.f, 0.f, 0.f, 0.f};
#pragma unroll
  for (int i = 0; i < 4; ++i)
#pragma unroll
    for (int j = 0; j < 2; ++j) acc[i][j] = z4;

#define SA(G, KT, BUF) gload16(Asrc + (G) * 65536 + (KT) * 64, &Alds[BUF][((G) * 512 + tid) * 8])
#define SB(G, KT, BUF) gload16(Bsrc + (G) * 65536 + (KT) * 64, &Blds[BUF][((G) * 512 + tid) * 8])
#define LOADAB(SC) do {                                                            \
    _Pragma("unroll") for (int ii = 0; ii < 4; ++ii)                               \
      af[ii] = *(const bf16x8*)&Alds[cb][baseA + ii * 1024 + (SC)];                \
    _Pragma("unroll") for (int j = 0; j < 2; ++j)                                  \
      bf[j] = *(const bf16x8*)&Blds[cb][baseB + j * 1024 + (SC)];                  \
  } while (0)
#define MF() do {                                                                  \
    _Pragma("unroll") for (int ii = 0; ii < 4; ++ii)                               \
      _Pragma("unroll") for (int j = 0; j < 2; ++j)                                \
        acc[ii][j] = __builtin_amdgcn_mfma_f32_16x16x32_bf16(af[ii], bf[j],        \
                                                             acc[ii][j], 0, 0, 0); \
  } while (0)

  // prologue: stage tile 0 (4 loads/thread)
  SA(0, 0, 0); SA(1, 0, 0); SB(0, 0, 0); SB(1, 0, 0);

  for (int kt = 0; kt < 16; ++kt) {
    const int cb = kt & 1, nb = cb ^ 1;
    const bool st = (kt < 15);
    asm volatile("s_waitcnt vmcnt(0)" ::: "memory");   // all stages of tile kt landed
    __builtin_amdgcn_s_barrier();
    __builtin_amdgcn_sched_barrier(0);
    bf16x8 af[4], bf[2];
    // phase 0: kh0
    LOADAB(sc0);
    if (st) { SA(0, kt + 1, nb); SA(1, kt + 1, nb); }
    __builtin_amdgcn_s_barrier();
    asm volatile("s_waitcnt lgkmcnt(0)" ::: "memory");
    __builtin_amdgcn_sched_barrier(0);
    __builtin_amdgcn_s_setprio(1);
    MF();
    __builtin_amdgcn_s_setprio(0);
    __builtin_amdgcn_s_barrier();
    // phase 1: kh1
    LOADAB(sc1);
    if (st) { SB(0, kt + 1, nb); SB(1, kt + 1, nb); }
    __builtin_amdgcn_s_barrier();
    asm volatile("s_waitcnt lgkmcnt(0)" ::: "memory");
    __builtin_amdgcn_sched_barrier(0);
    __builtin_amdgcn_s_setprio(1);
    MF();
    __builtin_amdgcn_s_setprio(0);
    __builtin_amdgcn_s_barrier();
  }
#undef SA
#undef SB
#undef LOADAB
#undef MF

#pragma unroll
  for (int i = 0; i < 4; ++i)
#pragma unroll
    for (int j = 0; j < 2; ++j) {
      const int e0 = ra0 + wm * 64 + i * 16 + lg * 4;
      const int m = rb0 + wn * 32 + j * 16 + lq;
      *(f32x4*)&out[m * 1024 + e0] = acc[i][j];
    }
}

// ---------------- flash attention: 8 waves x 16 q-rows, KVBLK=128, batched-QK inner (R16) -------
__global__ __launch_bounds__(512, 4) void attn_kernel(const u16* __restrict__ Q,
                                                      const u16* __restrict__ K,
                                                      const u16* __restrict__ Vt,
                                                      u16* __restrict__ Z) {
  __shared__ __align__(16) u16 Ktile[2][8192];   // 128 keys x 64 d, chunk-swizzled (mod-8)
  __shared__ __align__(16) u16 Vtile[2][8192];   // 64 d x 128 keys, chunk-swizzled (mod-16)
  const int tid = threadIdx.x;
  const int wv = tid >> 6, ln = tid & 63;
  const int lq = ln & 15, lg = ln >> 4;
  const bool lgodd = (lg & 1) != 0;
  const int id = blockIdx.x;
  const int within = id >> 3;                      // 0..63
  const int xg = id & 7;                           // XCD group (L2 locality)
  int bh, qt;
  if (within < 32) { bh = xg * 4 + (within >> 4);     qt = 15 - (within & 15); }
  else { const int w = within - 32; bh = xg * 4 + 2 + (w >> 4); qt = w & 15; }
  const int qrow = (qt << 7) + wv * 16 + lq;       // this thread's q row
  const u16* Qp = Q + (size_t)bh * S_ * Dh_;
  const u16* Kp = K + (size_t)bh * S_ * Dh_;
  const u16* Vp = Vt + (size_t)bh * Dh_ * S_;

  // staging: 1024 16B-chunks per tile kind; 512 threads x 2 chunks each
  int kgofs[2], vgrow[2], vgcol[2];
#pragma unroll
  for (int j = 0; j < 2; ++j) {
    const int p = j * 512 + tid;                   // 0..1023 chunk id
    const int gk = p ^ ((p >> 3) & 7);             // K: row=p>>3 (0..127), col swizzled mod 8
    kgofs[j] = (gk >> 3) * 64 + (gk & 7) * 8;
    vgrow[j] = p >> 4;                             // V: row=d (0..63), col swizzled mod 16
    vgcol[j] = ((p & 15) ^ ((p >> 4) & 15)) * 8;
  }
  const int sc0 = (lg ^ (lq & 7)) * 8;             // K read cols (d-half 0)
  const int sc1 = ((4 + lg) ^ (lq & 7)) * 8;       // K read cols (d-half 1)

  bf16x8 qf0 = *(const bf16x8*)&Qp[qrow * Dh_ + lg * 8];
  bf16x8 qf1 = *(const bf16x8*)&Qp[qrow * Dh_ + 32 + lg * 8];

  f32x4 o[4];
  const f32x4 z4 = {0.f, 0.f, 0.f, 0.f};
#pragma unroll
  for (int dt = 0; dt < 4; ++dt) o[dt] = z4;
  float l_lane = 0.f;

#define STAGE(KT, BUF) do { const int kb_ = (KT) * 128;                              \
    gload16(Kp + (size_t)kb_ * 64 + kgofs[0], &Ktile[BUF][wv * 512]);                \
    gload16(Kp + (size_t)kb_ * 64 + kgofs[1], &Ktile[BUF][4096 + wv * 512]);         \
    gload16(Vp + (size_t)vgrow[0] * 2048 + kb_ + vgcol[0], &Vtile[BUF][wv * 512]);   \
    gload16(Vp + (size_t)vgrow[1] * 2048 + kb_ + vgcol[1], &Vtile[BUF][4096 + wv * 512]); \
  } while (0)

  STAGE(0, 0);

  int cur = 0;
  for (int kt = 0; kt <= qt; ++kt) {
    asm volatile("s_waitcnt vmcnt(0)" ::: "memory");   // own stage of tile kt drained
    __builtin_amdgcn_s_barrier();                      // all stages landed; old reads done
    __builtin_amdgcn_sched_barrier(0);
    if (kt < qt) STAGE(kt + 1, cur ^ 1);
    const int k0 = kt * 128;
    const bool diag = (kt == qt);
    const int nkk = diag ? ((wv >> 1) + 1) : 4;    // diag: skip fully-masked 32-key slices

    // ---- pass 1: batched QK^T for all live slices (fills MFMA pipe) ----
    f32x4 sa[4], sb[4];
    __builtin_amdgcn_s_setprio(1);
#pragma unroll
    for (int kk = 0; kk < 4; ++kk) {
      if (kk < nkk) {
        const int rA = (kk * 32 + lq) * 64;        // keys kk*32 + 0..15
        const int rB = rA + 1024;                  // +16 keys
        bf16x8 kA0 = *(const bf16x8*)&Ktile[cur][rA + sc0];
        bf16x8 kA1 = *(const bf16x8*)&Ktile[cur][rA + sc1];
        bf16x8 kB0 = *(const bf16x8*)&Ktile[cur][rB + sc0];
        bf16x8 kB1 = *(const bf16x8*)&Ktile[cur][rB + sc1];
        f32x4 a = z4, b = z4;
        a = __builtin_amdgcn_mfma_f32_16x16x32_bf16(kA0, qf0, a, 0, 0, 0);
        a = __builtin_amdgcn_mfma_f32_16x16x32_bf16(kA1, qf1, a, 0, 0, 0);
        b = __builtin_amdgcn_mfma_f32_16x16x32_bf16(kB0, qf0, b, 0, 0, 0);
        b = __builtin_amdgcn_mfma_f32_16x16x32_bf16(kB1, qf1, b, 0, 0, 0);
        sa[kk] = a; sb[kk] = b;
      }
    }
    __builtin_amdgcn_s_setprio(0);

    // ---- pass 2: per-slice softmax + route + PV (V reads issue under exp2 chains) ----
#pragma unroll
    for (int kk = 0; kk < 4; ++kk) {
      if (kk < nkk) {
        f32x4 xa = sa[kk], xb = sb[kk];
        if (diag) {
          const int keyA = k0 + kk * 32 + lg * 4;
          const int keyB = keyA + 16;
#pragma unroll
          for (int r = 0; r < 4; ++r) {
            if (keyA + r > qrow) xa[r] = -3.0e38f;
            if (keyB + r > qrow) xb[r] = -3.0e38f;
          }
        }
        // fixed-max softmax (log2 domain; scores bounded, exp2 can't overflow)
        float e0 = __builtin_amdgcn_exp2f(xa[0]);
        float e1 = __builtin_amdgcn_exp2f(xa[1]);
        float e2 = __builtin_amdgcn_exp2f(xa[2]);
        float e3 = __builtin_amdgcn_exp2f(xa[3]);
        float f0 = __builtin_amdgcn_exp2f(xb[0]);
        float f1 = __builtin_amdgcn_exp2f(xb[1]);
        float f2 = __builtin_amdgcn_exp2f(xb[2]);
        float f3 = __builtin_amdgcn_exp2f(xb[3]);
        l_lane += ((e0 + e1) + (e2 + e3)) + ((f0 + f1) + (f2 + f3));
        u32 A0, A1, B0, B1;
        asm("v_cvt_pk_bf16_f32 %0, %1, %2" : "=v"(A0) : "v"(e0), "v"(e1));
        asm("v_cvt_pk_bf16_f32 %0, %1, %2" : "=v"(A1) : "v"(e2), "v"(e3));
        asm("v_cvt_pk_bf16_f32 %0, %1, %2" : "=v"(B0) : "v"(f0), "v"(f1));
        asm("v_cvt_pk_bf16_f32 %0, %1, %2" : "=v"(B1) : "v"(f2), "v"(f3));
        // in-register P^T routing (verified R6-R17)
        asm("v_permlane32_swap_b32 %0, %1" : "+v"(A0), "+v"(B0));
        asm("v_permlane32_swap_b32 %0, %1" : "+v"(A1), "+v"(B1));
        const u32 A0x = __shfl_xor((int)A0, 16), B0x = __shfl_xor((int)B0, 16);
        const u32 A1x = __shfl_xor((int)A1, 16), B1x = __shfl_xor((int)B1, 16);
        u32x4 w;
        w[0] = lgodd ? B0x : A0;
        w[1] = lgodd ? B1x : A1;
        w[2] = lgodd ? B0 : A0x;
        w[3] = lgodd ? B1 : A1x;
        const bf16x8 pf = __builtin_bit_cast(bf16x8, w);
        const int scvk = ((kk * 4 + lg) ^ lq) * 8;
        __builtin_amdgcn_s_setprio(1);
#pragma unroll
        for (int dt = 0; dt < 4; ++dt) {
          bf16x8 vf = *(const bf16x8*)&Vtile[cur][(dt * 16 + lq) * 128 + scvk];
          o[dt] = __builtin_amdgcn_mfma_f32_16x16x32_bf16(vf, pf, o[dt], 0, 0, 0);
        }
        __builtin_amdgcn_s_setprio(0);
      }
    }
    cur ^= 1;
  }
#undef STAGE

  // epilogue: reduce row-sum across lg groups, apply 1/l and the quirk's extra /8
  float l = l_lane;
  l += __shfl_xor(l, 16);
  l += __shfl_xor(l, 32);
  const float inv = 0.125f / l;
#pragma unroll
  for (int dt = 0; dt < 4; ++dt) {
    u16x4 pko;
#pragma unroll
    for (int r = 0; r < 4; ++r) pko[r] = f2bf(o[dt][r] * inv);
    *(u16x4*)&Z[((size_t)bh * S_ + qrow) * Dh_ + dt * 16 + lg * 4] = pko;
  }
}

extern "C" void kernel_launch(void* const* d_in, const int* in_sizes, int n_in,
                              void* d_out, int out_size, void* d_ws, size_t ws_size,
                              hipStream_t stream) {
  const float* x    = (const float*)d_in[0];
  const float* Wq   = (const float*)d_in[1];
  const float* bq   = (const float*)d_in[2];
  const float* Wk   = (const float*)d_in[3];
  const float* bk   = (const float*)d_in[4];
  const float* Wv   = (const float*)d_in[5];
  const float* bv   = (const float*)d_in[6];
  const float* proj = (const float*)d_in[7];
  float* out = (float*)d_out;

  char* p = (char*)d_ws;
  u16* xb   = (u16*)p; p += (size_t)4096 * 1024 * 2;
  u16* wcat = (u16*)p; p += (size_t)3072 * 1024 * 2;
  u16* pjt  = (u16*)p; p += (size_t)1024 * 1024 * 2;
  u16* Qb   = (u16*)p; p += (size_t)4096 * 1024 * 2;
  u16* Kb   = (u16*)p; p += (size_t)4096 * 1024 * 2;
  u16* Vtb  = (u16*)p; p += (size_t)4096 * 1024 * 2;
  u16* Zb   = (u16*)p; p += (size_t)4096 * 1024 * 2;

  cvt_all<<<dim3(4608), dim3(256), 0, stream>>>(x, Wq, Wk, Wv, proj, xb, wcat, pjt);

  const float qs = 0.125f * 1.44269504f;  // fold score-scale + log2e into Q
  qkv_gemm<<<dim3(512), dim3(512), 0, stream>>>(wcat, xb, bq, bk, bv, Qb, Kb, Vtb, qs);

  attn_kernel<<<dim3(512), dim3(512), 0, stream>>>(Qb, Kb, Vtb, Zb);

  proj_gemm<<<dim3(256), dim3(512), 0, stream>>>(pjt, Zb, out);
}

// Round 19
// 95.438 us; speedup vs baseline: 1.1286x; 1.0030x over previous
//
#include <hip/hip_runtime.h>
#include <hip/hip_bf16.h>

typedef unsigned short u16;
typedef unsigned int u32;
typedef __bf16 bf16x8 __attribute__((ext_vector_type(8)));
typedef float f32x4 __attribute__((ext_vector_type(4)));
typedef u16 u16x8 __attribute__((ext_vector_type(8)));
typedef u16 u16x4 __attribute__((ext_vector_type(4)));
typedef u32 u32x4 __attribute__((ext_vector_type(4)));

#define B_ 2
#define S_ 2048
#define E_ 1024
#define H_ 16
#define Dh_ 64

static __device__ __forceinline__ u16 f2bf(float f) {
  unsigned u = __builtin_bit_cast(unsigned, f);
  u += 0x7fff + ((u >> 16) & 1);   // RNE
  return (u16)(u >> 16);
}

static __device__ __forceinline__ void gload16(const u16* g, u16* l) {
  __builtin_amdgcn_global_load_lds((const __attribute__((address_space(1))) unsigned int*)g,
                                   (__attribute__((address_space(3))) unsigned int*)l,
                                   16, 0, 0);
}

// ---------------- fused fp32 -> bf16 convert: x, Wq|Wk|Wv -> wcat; proj -> projT ----------------
__global__ void cvt_all(const float* __restrict__ x, const float* __restrict__ wq,
                        const float* __restrict__ wk, const float* __restrict__ wv,
                        const float* __restrict__ proj,
                        u16* __restrict__ xb, u16* __restrict__ wcat, u16* __restrict__ pjt) {
  __shared__ float tt[32][33];
  const int bid = blockIdx.x;
  const int tid = threadIdx.x;
  if (bid < 3584) {
    const int i = bid * 256 + tid;                   // 0..917503, exact
    const float* src; u16x8* dst;
    if (i < 524288) {
      src = x + (size_t)i * 8;            dst = (u16x8*)xb + i;
    } else {
      const int j = i - 524288;                      // 0..393215
      dst = (u16x8*)wcat + j;
      if (j < 131072)      src = wq + (size_t)j * 8;
      else if (j < 262144) src = wk + (size_t)(j - 131072) * 8;
      else                 src = wv + (size_t)(j - 262144) * 8;
    }
    float4 a = ((const float4*)src)[0], b = ((const float4*)src)[1];
    u16x8 o;
    o[0] = f2bf(a.x); o[1] = f2bf(a.y); o[2] = f2bf(a.z); o[3] = f2bf(a.w);
    o[4] = f2bf(b.x); o[5] = f2bf(b.y); o[6] = f2bf(b.z); o[7] = f2bf(b.w);
    *dst = o;
  } else {
    const int tb = bid - 3584;                       // 0..1023
    const int e0 = (tb & 31) * 32, f0 = (tb >> 5) * 32;
    const int tx = tid & 31, ty = tid >> 5;          // 32 x 8
#pragma unroll
    for (int r = 0; r < 4; ++r) {
      const int row = ty + r * 8;
      tt[row][tx] = proj[(f0 + row) * 1024 + e0 + tx];
    }
    __syncthreads();
#pragma unroll
    for (int r = 0; r < 4; ++r) {
      const int row = ty + r * 8;
      pjt[(e0 + row) * 1024 + f0 + tx] = f2bf(tt[tx][row]);
    }
  }
}

// ---------------- fused QKV GEMM: 192x128 tile, 8 waves, 2-phase/K-tile, grid 512 (R18) -------
__global__ __launch_bounds__(512, 4) void qkv_gemm(const u16* __restrict__ Wcat,
                                                   const u16* __restrict__ Xm,
                                                   const float* __restrict__ bq,
                                                   const float* __restrict__ bk,
                                                   const float* __restrict__ bv,
                                                   u16* __restrict__ Qb, u16* __restrict__ Kb,
                                                   u16* __restrict__ Vtb, float qs) {
  __shared__ __align__(16) u16 Alds[2][12288];   // 192 rows x 64 k
  __shared__ __align__(16) u16 Blds[2][8192];    // 128 rows x 64 k
  const int tid = threadIdx.x;                   // 0..511
  const int wv = tid >> 6, ln = tid & 63;
  const int lq = ln & 15, lg = ln >> 4;
  const int wm = wv >> 2, wn = wv & 3;           // wave grid 2(M) x 4(N)
  const int bid = blockIdx.x;
  const int xcd = bid & 7, w = bid >> 3;         // w 0..63
  const int bx = w & 15;                         // 0..15 (M tiles of 192)
  const int by = xcd * 4 + (w >> 4);             // 0..31 (N tiles of 128)
  const int ra0 = bx * 192, rb0 = by * 128;

  // staging: thread t stages LDS chunk G*512+t; source col pre-swizzled (c ^ row&7)
  const int r_t = tid >> 3, c_t = tid & 7;       // row-in-group 0..63, chunk 0..7
  const int gcol = (c_t ^ (r_t & 7)) * 8;        // swizzled source k-offset (u16)
  const u16* Asrc = Wcat + (ra0 + r_t) * 1024 + gcol;
  const u16* Bsrc = Xm   + (rb0 + r_t) * 1024 + gcol;

  // fragment read offsets (swizzled): chunk pos = (kh*4+lg) ^ (lq&7)
  const int sc0 = (lg ^ (lq & 7)) * 8;
  const int sc1 = ((4 + lg) ^ (lq & 7)) * 8;
  const int baseA = (wm * 96 + lq) * 64;         // + ii*1024 + sc
  const int baseB = (wn * 32 + lq) * 64;         // + j*1024 + sc

  f32x4 acc[6][2];
  const f32x4 z4 = {0.f, 0.f, 0.f, 0.f};
#pragma unroll
  for (int i = 0; i < 6; ++i)
#pragma unroll
    for (int j = 0; j < 2; ++j) acc[i][j] = z4;

#define SA(G, KT, BUF) gload16(Asrc + (G) * 65536 + (KT) * 64, &Alds[BUF][((G) * 512 + tid) * 8])
#define SB(G, KT, BUF) gload16(Bsrc + (G) * 65536 + (KT) * 64, &Blds[BUF][((G) * 512 + tid) * 8])
#define LOADAB(SC) do {                                                            \
    _Pragma("unroll") for (int ii = 0; ii < 6; ++ii)                               \
      af[ii] = *(const bf16x8*)&Alds[cb][baseA + ii * 1024 + (SC)];                \
    _Pragma("unroll") for (int j = 0; j < 2; ++j)                                  \
      bfr[j] = *(const bf16x8*)&Blds[cb][baseB + j * 1024 + (SC)];                 \
  } while (0)
#define MF() do {                                                                  \
    _Pragma("unroll") for (int ii = 0; ii < 6; ++ii)                               \
      _Pragma("unroll") for (int j = 0; j < 2; ++j)                                \
        acc[ii][j] = __builtin_amdgcn_mfma_f32_16x16x32_bf16(af[ii], bfr[j],       \
                                                             acc[ii][j], 0, 0, 0); \
  } while (0)

  // prologue: stage tile 0 (5 loads/thread: A groups 0..2, B groups 0..1)
  SA(0, 0, 0); SA(1, 0, 0); SA(2, 0, 0); SB(0, 0, 0); SB(1, 0, 0);

  for (int kt = 0; kt < 16; ++kt) {
    const int cb = kt & 1, nb = cb ^ 1;
    const bool st = (kt < 15);
    asm volatile("s_waitcnt vmcnt(0)" ::: "memory");   // all stages of tile kt landed
    __builtin_amdgcn_s_barrier();
    __builtin_amdgcn_sched_barrier(0);
    bf16x8 af[6], bfr[2];
    // phase 0: kh0
    LOADAB(sc0);
    if (st) { SA(0, kt + 1, nb); SA(1, kt + 1, nb); SA(2, kt + 1, nb); }
    __builtin_amdgcn_s_barrier();
    asm volatile("s_waitcnt lgkmcnt(0)" ::: "memory");
    __builtin_amdgcn_sched_barrier(0);
    __builtin_amdgcn_s_setprio(1);
    MF();
    __builtin_amdgcn_s_setprio(0);
    __builtin_amdgcn_s_barrier();
    // phase 1: kh1
    LOADAB(sc1);
    if (st) { SB(0, kt + 1, nb); SB(1, kt + 1, nb); }
    __builtin_amdgcn_s_barrier();
    asm volatile("s_waitcnt lgkmcnt(0)" ::: "memory");
    __builtin_amdgcn_sched_barrier(0);
    __builtin_amdgcn_s_setprio(1);
    MF();
    __builtin_amdgcn_s_setprio(0);
    __builtin_amdgcn_s_barrier();
  }
#undef SA
#undef SB
#undef LOADAB
#undef MF

  // epilogue: region per fragment (16-row frags never straddle a 1024 boundary)
#pragma unroll
  for (int i = 0; i < 6; ++i) {
    const int n0 = ra0 + wm * 96 + i * 16 + lg * 4;
    const int reg_i = n0 >> 10;                  // 0=Q 1=K 2=V, wave-uniform per frag
    const int nl = n0 & 1023;
    const int h = nl >> 6, d = nl & 63;
    const float* bias = (reg_i == 0) ? bq : (reg_i == 1) ? bk : bv;
    const float osc = (reg_i == 0) ? qs : 1.0f;
    const float4 b4 = *(const float4*)&bias[nl];
#pragma unroll
    for (int j = 0; j < 2; ++j) {
      const int m = rb0 + wn * 32 + j * 16 + lq;
      const int bb = m >> 11, s = m & 2047;
      if (reg_i < 2) {
        u16* out = (reg_i == 0) ? Qb : Kb;
        u16x4 pk;
        pk[0] = f2bf((acc[i][j][0] + b4.x) * osc);
        pk[1] = f2bf((acc[i][j][1] + b4.y) * osc);
        pk[2] = f2bf((acc[i][j][2] + b4.z) * osc);
        pk[3] = f2bf((acc[i][j][3] + b4.w) * osc);
        *(u16x4*)&out[((bb * H_ + h) * S_ + s) * Dh_ + d] = pk;
      } else {
        const float bvv[4] = {b4.x, b4.y, b4.z, b4.w};
#pragma unroll
        for (int r = 0; r < 4; ++r)
          Vtb[((bb * H_ + h) * Dh_ + d + r) * S_ + s] = f2bf(acc[i][j][r] + bvv[r]);
      }
    }
  }
}

// ---------------- proj GEMM: 128(e)x64(m) tile, 4 waves (2x2), grid 512 (3 blocks/CU) ----------
// out[m][e] = sum_k pjt[e][k] * Z[m][k]. LDS 48 KB -> 3 blocks/CU = 3 waves/SIMD.
__global__ __launch_bounds__(256, 3) void proj_gemm(const u16* __restrict__ Am,
                                                    const u16* __restrict__ Bm,
                                                    float* __restrict__ out) {
  __shared__ __align__(16) u16 Alds[2][8192];    // 128 rows x 64 k
  __shared__ __align__(16) u16 Blds[2][4096];    // 64 rows x 64 k
  const int tid = threadIdx.x;                   // 0..255
  const int wv = tid >> 6, ln = tid & 63;
  const int lq = ln & 15, lg = ln >> 4;
  const int wm = wv >> 1, wn = wv & 1;           // wave grid 2(M=e) x 2(N=m)
  const int bid = blockIdx.x;
  const int xcd = bid & 7, w = bid >> 3;         // w 0..63
  const int bx = w & 7;                          // 0..7  (e tiles of 128)
  const int by = xcd * 8 + (w >> 3);             // 0..63 (m tiles of 64)
  const int ra0 = bx * 128, rb0 = by * 64;

  // staging: 256 threads; A rows tid>>3 + {0,32,64,96} (4 loads), B rows tid>>3 + {0,32} (2)
  const int r_t = tid >> 3, c_t = tid & 7;
  const int gcol = (c_t ^ (r_t & 7)) * 8;        // row&7 invariant under +32
  const u16* Asrc = Am + (ra0 + r_t) * 1024 + gcol;
  const u16* Bsrc = Bm + (rb0 + r_t) * 1024 + gcol;

  const int sc0 = (lg ^ (lq & 7)) * 8;
  const int sc1 = ((4 + lg) ^ (lq & 7)) * 8;
  const int baseA = (wm * 64 + lq) * 64;         // + ii*1024 + sc
  const int baseB = (wn * 32 + lq) * 64;         // + j*1024 + sc

  f32x4 acc[4][2];
  const f32x4 z4 = {0.f, 0.f, 0.f, 0.f};
#pragma unroll
  for (int i = 0; i < 4; ++i)
#pragma unroll
    for (int j = 0; j < 2; ++j) acc[i][j] = z4;

#define SA(G, KT, BUF) \
  gload16(Asrc + (G) * 32768 + (KT) * 64, &Alds[BUF][((G) * 256 + tid) * 8])
#define SB(G, KT, BUF) \
  gload16(Bsrc + (G) * 32768 + (KT) * 64, &Blds[BUF][((G) * 256 + tid) * 8])
#define LOADAB(SC) do {                                                            \
    _Pragma("unroll") for (int ii = 0; ii < 4; ++ii)                               \
      af[ii] = *(const bf16x8*)&Alds[cb][baseA + ii * 1024 + (SC)];                \
    _Pragma("unroll") for (int j = 0; j < 2; ++j)                                  \
      bf[j] = *(const bf16x8*)&Blds[cb][baseB + j * 1024 + (SC)];                  \
  } while (0)
#define MF() do {                                                                  \
    _Pragma("unroll") for (int ii = 0; ii < 4; ++ii)                               \
      _Pragma("unroll") for (int j = 0; j < 2; ++j)                                \
        acc[ii][j] = __builtin_amdgcn_mfma_f32_16x16x32_bf16(af[ii], bf[j],        \
                                                             acc[ii][j], 0, 0, 0); \
  } while (0)

  // prologue: stage tile 0 (6 loads/thread)
  SA(0, 0, 0); SA(1, 0, 0); SA(2, 0, 0); SA(3, 0, 0); SB(0, 0, 0); SB(1, 0, 0);

  for (int kt = 0; kt < 16; ++kt) {
    const int cb = kt & 1, nb = cb ^ 1;
    const bool st = (kt < 15);
    asm volatile("s_waitcnt vmcnt(0)" ::: "memory");   // all stages of tile kt landed
    __builtin_amdgcn_s_barrier();
    __builtin_amdgcn_sched_barrier(0);
    bf16x8 af[4], bf[2];
    // phase 0: kh0
    LOADAB(sc0);
    if (st) { SA(0, kt + 1, nb); SA(1, kt + 1, nb); SA(2, kt + 1, nb); }
    __builtin_amdgcn_s_barrier();
    asm volatile("s_waitcnt lgkmcnt(0)" ::: "memory");
    __builtin_amdgcn_sched_barrier(0);
    __builtin_amdgcn_s_setprio(1);
    MF();
    __builtin_amdgcn_s_setprio(0);
    __builtin_amdgcn_s_barrier();
    // phase 1: kh1
    LOADAB(sc1);
    if (st) { SA(3, kt + 1, nb); SB(0, kt + 1, nb); SB(1, kt + 1, nb); }
    __builtin_amdgcn_s_barrier();
    asm volatile("s_waitcnt lgkmcnt(0)" ::: "memory");
    __builtin_amdgcn_sched_barrier(0);
    __builtin_amdgcn_s_setprio(1);
    MF();
    __builtin_amdgcn_s_setprio(0);
    __builtin_amdgcn_s_barrier();
  }
#undef SA
#undef SB
#undef LOADAB
#undef MF

#pragma unroll
  for (int i = 0; i < 4; ++i)
#pragma unroll
    for (int j = 0; j < 2; ++j) {
      const int e0 = ra0 + wm * 64 + i * 16 + lg * 4;
      const int m = rb0 + wn * 32 + j * 16 + lq;
      *(f32x4*)&out[m * 1024 + e0] = acc[i][j];
    }
}

// ---------------- flash attention: 8 waves x 16 q-rows, KVBLK=128, batched-QK inner (R16) -------
__global__ __launch_bounds__(512, 4) void attn_kernel(const u16* __restrict__ Q,
                                                      const u16* __restrict__ K,
                                                      const u16* __restrict__ Vt,
                                                      u16* __restrict__ Z) {
  __shared__ __align__(16) u16 Ktile[2][8192];   // 128 keys x 64 d, chunk-swizzled (mod-8)
  __shared__ __align__(16) u16 Vtile[2][8192];   // 64 d x 128 keys, chunk-swizzled (mod-16)
  const int tid = threadIdx.x;
  const int wv = tid >> 6, ln = tid & 63;
  const int lq = ln & 15, lg = ln >> 4;
  const bool lgodd = (lg & 1) != 0;
  const int id = blockIdx.x;
  const int within = id >> 3;                      // 0..63
  const int xg = id & 7;                           // XCD group (L2 locality)
  int bh, qt;
  if (within < 32) { bh = xg * 4 + (within >> 4);     qt = 15 - (within & 15); }
  else { const int w = within - 32; bh = xg * 4 + 2 + (w >> 4); qt = w & 15; }
  const int qrow = (qt << 7) + wv * 16 + lq;       // this thread's q row
  const u16* Qp = Q + (size_t)bh * S_ * Dh_;
  const u16* Kp = K + (size_t)bh * S_ * Dh_;
  const u16* Vp = Vt + (size_t)bh * Dh_ * S_;

  // staging: 1024 16B-chunks per tile kind; 512 threads x 2 chunks each
  int kgofs[2], vgrow[2], vgcol[2];
#pragma unroll
  for (int j = 0; j < 2; ++j) {
    const int p = j * 512 + tid;                   // 0..1023 chunk id
    const int gk = p ^ ((p >> 3) & 7);             // K: row=p>>3 (0..127), col swizzled mod 8
    kgofs[j] = (gk >> 3) * 64 + (gk & 7) * 8;
    vgrow[j] = p >> 4;                             // V: row=d (0..63), col swizzled mod 16
    vgcol[j] = ((p & 15) ^ ((p >> 4) & 15)) * 8;
  }
  const int sc0 = (lg ^ (lq & 7)) * 8;             // K read cols (d-half 0)
  const int sc1 = ((4 + lg) ^ (lq & 7)) * 8;       // K read cols (d-half 1)

  bf16x8 qf0 = *(const bf16x8*)&Qp[qrow * Dh_ + lg * 8];
  bf16x8 qf1 = *(const bf16x8*)&Qp[qrow * Dh_ + 32 + lg * 8];

  f32x4 o[4];
  const f32x4 z4 = {0.f, 0.f, 0.f, 0.f};
#pragma unroll
  for (int dt = 0; dt < 4; ++dt) o[dt] = z4;
  float l_lane = 0.f;

#define STAGE(KT, BUF) do { const int kb_ = (KT) * 128;                              \
    gload16(Kp + (size_t)kb_ * 64 + kgofs[0], &Ktile[BUF][wv * 512]);                \
    gload16(Kp + (size_t)kb_ * 64 + kgofs[1], &Ktile[BUF][4096 + wv * 512]);         \
    gload16(Vp + (size_t)vgrow[0] * 2048 + kb_ + vgcol[0], &Vtile[BUF][wv * 512]);   \
    gload16(Vp + (size_t)vgrow[1] * 2048 + kb_ + vgcol[1], &Vtile[BUF][4096 + wv * 512]); \
  } while (0)

  STAGE(0, 0);

  int cur = 0;
  for (int kt = 0; kt <= qt; ++kt) {
    asm volatile("s_waitcnt vmcnt(0)" ::: "memory");   // own stage of tile kt drained
    __builtin_amdgcn_s_barrier();                      // all stages landed; old reads done
    __builtin_amdgcn_sched_barrier(0);
    if (kt < qt) STAGE(kt + 1, cur ^ 1);
    const int k0 = kt * 128;
    const bool diag = (kt == qt);
    const int nkk = diag ? ((wv >> 1) + 1) : 4;    // diag: skip fully-masked 32-key slices

    // ---- pass 1: batched QK^T for all live slices (fills MFMA pipe) ----
    f32x4 sa[4], sb[4];
    __builtin_amdgcn_s_setprio(1);
#pragma unroll
    for (int kk = 0; kk < 4; ++kk) {
      if (kk < nkk) {
        const int rA = (kk * 32 + lq) * 64;        // keys kk*32 + 0..15
        const int rB = rA + 1024;                  // +16 keys
        bf16x8 kA0 = *(const bf16x8*)&Ktile[cur][rA + sc0];
        bf16x8 kA1 = *(const bf16x8*)&Ktile[cur][rA + sc1];
        bf16x8 kB0 = *(const bf16x8*)&Ktile[cur][rB + sc0];
        bf16x8 kB1 = *(const bf16x8*)&Ktile[cur][rB + sc1];
        f32x4 a = z4, b = z4;
        a = __builtin_amdgcn_mfma_f32_16x16x32_bf16(kA0, qf0, a, 0, 0, 0);
        a = __builtin_amdgcn_mfma_f32_16x16x32_bf16(kA1, qf1, a, 0, 0, 0);
        b = __builtin_amdgcn_mfma_f32_16x16x32_bf16(kB0, qf0, b, 0, 0, 0);
        b = __builtin_amdgcn_mfma_f32_16x16x32_bf16(kB1, qf1, b, 0, 0, 0);
        sa[kk] = a; sb[kk] = b;
      }
    }
    __builtin_amdgcn_s_setprio(0);

    // ---- pass 2: per-slice softmax + route + PV (V reads issue under exp2 chains) ----
#pragma unroll
    for (int kk = 0; kk < 4; ++kk) {
      if (kk < nkk) {
        f32x4 xa = sa[kk], xb = sb[kk];
        if (diag) {
          const int keyA = k0 + kk * 32 + lg * 4;
          const int keyB = keyA + 16;
#pragma unroll
          for (int r = 0; r < 4; ++r) {
            if (keyA + r > qrow) xa[r] = -3.0e38f;
            if (keyB + r > qrow) xb[r] = -3.0e38f;
          }
        }
        // fixed-max softmax (log2 domain; scores bounded, exp2 can't overflow)
        float e0 = __builtin_amdgcn_exp2f(xa[0]);
        float e1 = __builtin_amdgcn_exp2f(xa[1]);
        float e2 = __builtin_amdgcn_exp2f(xa[2]);
        float e3 = __builtin_amdgcn_exp2f(xa[3]);
        float f0 = __builtin_amdgcn_exp2f(xb[0]);
        float f1 = __builtin_amdgcn_exp2f(xb[1]);
        float f2 = __builtin_amdgcn_exp2f(xb[2]);
        float f3 = __builtin_amdgcn_exp2f(xb[3]);
        l_lane += ((e0 + e1) + (e2 + e3)) + ((f0 + f1) + (f2 + f3));
        u32 A0, A1, B0, B1;
        asm("v_cvt_pk_bf16_f32 %0, %1, %2" : "=v"(A0) : "v"(e0), "v"(e1));
        asm("v_cvt_pk_bf16_f32 %0, %1, %2" : "=v"(A1) : "v"(e2), "v"(e3));
        asm("v_cvt_pk_bf16_f32 %0, %1, %2" : "=v"(B0) : "v"(f0), "v"(f1));
        asm("v_cvt_pk_bf16_f32 %0, %1, %2" : "=v"(B1) : "v"(f2), "v"(f3));
        // in-register P^T routing (verified R6-R18)
        asm("v_permlane32_swap_b32 %0, %1" : "+v"(A0), "+v"(B0));
        asm("v_permlane32_swap_b32 %0, %1" : "+v"(A1), "+v"(B1));
        const u32 A0x = __shfl_xor((int)A0, 16), B0x = __shfl_xor((int)B0, 16);
        const u32 A1x = __shfl_xor((int)A1, 16), B1x = __shfl_xor((int)B1, 16);
        u32x4 w;
        w[0] = lgodd ? B0x : A0;
        w[1] = lgodd ? B1x : A1;
        w[2] = lgodd ? B0 : A0x;
        w[3] = lgodd ? B1 : A1x;
        const bf16x8 pf = __builtin_bit_cast(bf16x8, w);
        const int scvk = ((kk * 4 + lg) ^ lq) * 8;
        __builtin_amdgcn_s_setprio(1);
#pragma unroll
        for (int dt = 0; dt < 4; ++dt) {
          bf16x8 vf = *(const bf16x8*)&Vtile[cur][(dt * 16 + lq) * 128 + scvk];
          o[dt] = __builtin_amdgcn_mfma_f32_16x16x32_bf16(vf, pf, o[dt], 0, 0, 0);
        }
        __builtin_amdgcn_s_setprio(0);
      }
    }
    cur ^= 1;
  }
#undef STAGE

  // epilogue: reduce row-sum across lg groups, apply 1/l and the quirk's extra /8
  float l = l_lane;
  l += __shfl_xor(l, 16);
  l += __shfl_xor(l, 32);
  const float inv = 0.125f / l;
#pragma unroll
  for (int dt = 0; dt < 4; ++dt) {
    u16x4 pko;
#pragma unroll
    for (int r = 0; r < 4; ++r) pko[r] = f2bf(o[dt][r] * inv);
    *(u16x4*)&Z[((size_t)bh * S_ + qrow) * Dh_ + dt * 16 + lg * 4] = pko;
  }
}

extern "C" void kernel_launch(void* const* d_in, const int* in_sizes, int n_in,
                              void* d_out, int out_size, void* d_ws, size_t ws_size,
                              hipStream_t stream) {
  const float* x    = (const float*)d_in[0];
  const float* Wq   = (const float*)d_in[1];
  const float* bq   = (const float*)d_in[2];
  const float* Wk   = (const float*)d_in[3];
  const float* bk   = (const float*)d_in[4];
  const float* Wv   = (const float*)d_in[5];
  const float* bv   = (const float*)d_in[6];
  const float* proj = (const float*)d_in[7];
  float* out = (float*)d_out;

  char* p = (char*)d_ws;
  u16* xb   = (u16*)p; p += (size_t)4096 * 1024 * 2;
  u16* wcat = (u16*)p; p += (size_t)3072 * 1024 * 2;
  u16* pjt  = (u16*)p; p += (size_t)1024 * 1024 * 2;
  u16* Qb   = (u16*)p; p += (size_t)4096 * 1024 * 2;
  u16* Kb   = (u16*)p; p += (size_t)4096 * 1024 * 2;
  u16* Vtb  = (u16*)p; p += (size_t)4096 * 1024 * 2;
  u16* Zb   = (u16*)p; p += (size_t)4096 * 1024 * 2;

  cvt_all<<<dim3(4608), dim3(256), 0, stream>>>(x, Wq, Wk, Wv, proj, xb, wcat, pjt);

  const float qs = 0.125f * 1.44269504f;  // fold score-scale + log2e into Q
  qkv_gemm<<<dim3(512), dim3(512), 0, stream>>>(wcat, xb, bq, bk, bv, Qb, Kb, Vtb, qs);

  attn_kernel<<<dim3(512), dim3(512), 0, stream>>>(Qb, Kb, Vtb, Zb);

  proj_gemm<<<dim3(512), dim3(256), 0, stream>>>(pjt, Zb, out);
}